// Round 2
// baseline (494.674 us; speedup 1.0000x reference)
//
#include <hip/hip_runtime.h>
#include <hip/hip_bf16.h>

typedef short bf16x8 __attribute__((ext_vector_type(8)));
typedef float f32x4 __attribute__((ext_vector_type(4)));

#define MFMA_BF16(A,B,C) __builtin_amdgcn_mfma_f32_16x16x32_bf16((A),(B),(C),0,0,0)

__device__ __forceinline__ unsigned short f2bf(float f){
    union { float f; unsigned u; } v; v.f = f;
    unsigned r = v.u + 0x7fffu + ((v.u >> 16) & 1u);
    return (unsigned short)(r >> 16);
}
__device__ __forceinline__ float bf2f(unsigned short h){
    union { unsigned u; float f; } v; v.u = ((unsigned)h) << 16; return v.f;
}

// ---------------- prep kernels ----------------
// split cast: hi = bf16(v), lo = bf16(v - hi)
__global__ __launch_bounds__(256) void k_cvt_split(const float* __restrict__ in,
                                                   unsigned short* __restrict__ hi,
                                                   unsigned short* __restrict__ lo, int n){
    int i = blockIdx.x * 256 + threadIdx.x;
    if (i < n) {
        float v = in[i];
        unsigned short h = f2bf(v);
        hi[i] = h;
        lo[i] = f2bf(v - bf2f(h));
    }
}

// Fused QKV weight, transposed, split hi/lo: out[c*512 + d], c = t*512+h*64+k
__global__ __launch_bounds__(256) void k_prep_qkvT(const float* __restrict__ Wq,
                                                   const float* __restrict__ Wk,
                                                   const float* __restrict__ Wv,
                                                   unsigned short* __restrict__ hi,
                                                   unsigned short* __restrict__ lo){
    int idx = blockIdx.x * 256 + threadIdx.x;   // [0, 1536*512)
    int c = idx >> 9, d = idx & 511;
    int t = c >> 9, rem = c & 511;
    int h = rem >> 6, k = rem & 63;
    const float* W = (t == 0) ? Wq : (t == 1) ? Wk : Wv;
    float v = W[(h * 512 + d) * 64 + k];
    unsigned short hh = f2bf(v);
    hi[idx] = hh;
    lo[idx] = f2bf(v - bf2f(hh));
}

// Generic transpose+cast: W is (D,N) row-major f32; out is (N,D) row-major bf16
__global__ __launch_bounds__(256) void k_prep_T(const float* __restrict__ W,
                                                unsigned short* __restrict__ out, int D, int N){
    int idx = blockIdx.x * 256 + threadIdx.x;   // [0, N*D)
    int n = idx / D, d = idx - n * D;
    out[idx] = f2bf(W[d * N + n]);
}

// ---------------- GEMM: C = A(MxK) * Bt(NxK)^T ----------------
// EPI: 0 = bf16 out, 1 = bias+relu bf16 out, 2 = bias f32 out, 3 = QKV split scatter
template<int EPI, bool SPLIT>
__global__ __launch_bounds__(256)
void gemm_bt(const unsigned short* __restrict__ Ah, const unsigned short* __restrict__ Al,
             const unsigned short* __restrict__ Bh, const unsigned short* __restrict__ Bl,
             int M, int N, int K, const float* __restrict__ bias,
             unsigned short* __restrict__ Cb, float* __restrict__ Cf,
             unsigned short* __restrict__ Qh, unsigned short* __restrict__ Ql,
             unsigned short* __restrict__ Kh, unsigned short* __restrict__ Kl,
             unsigned short* __restrict__ Vo)
{
    constexpr int BK = 32, LDP = 40;            // pad 32->40 elems: 2-way max bank conflict
    constexpr int NS = SPLIT ? 2 : 1;
    __shared__ __align__(16) unsigned short As[NS][128][LDP];
    __shared__ __align__(16) unsigned short Bs[NS][128][LDP];

    const int tid = threadIdx.x, lane = tid & 63, wave = tid >> 6;
    const int wr = wave >> 1, wc = wave & 1;
    const int bm = blockIdx.y, bn = blockIdx.x;
    const int rA0 = bm * 128, cB0 = bn * 128;
    const int fr = lane & 15, fg = lane >> 4;

    f32x4 acc[4][4];
    #pragma unroll
    for (int m = 0; m < 4; m++)
        #pragma unroll
        for (int n = 0; n < 4; n++)
            acc[m][n] = f32x4{0.f, 0.f, 0.f, 0.f};

    for (int kt = 0; kt < K; kt += BK) {
        __syncthreads();
        #pragma unroll
        for (int q = 0; q < 2; q++) {
            int ch = tid + q * 256;             // 512 chunks of 8 bf16
            int r = ch >> 2, kk = (ch & 3) << 3;
            size_t ga = (size_t)(rA0 + r) * K + kt + kk;
            size_t gb = (size_t)(cB0 + r) * K + kt + kk;
            *(uint4*)&As[0][r][kk] = *(const uint4*)&Ah[ga];
            *(uint4*)&Bs[0][r][kk] = *(const uint4*)&Bh[gb];
            if constexpr (SPLIT) {
                *(uint4*)&As[1][r][kk] = *(const uint4*)&Al[ga];
                *(uint4*)&Bs[1][r][kk] = *(const uint4*)&Bl[gb];
            }
        }
        __syncthreads();

        bf16x8 afh[4], bfh[4], afl[4], bfl[4];
        #pragma unroll
        for (int m = 0; m < 4; m++) afh[m] = *(const bf16x8*)&As[0][wr * 64 + m * 16 + fr][fg * 8];
        #pragma unroll
        for (int n = 0; n < 4; n++) bfh[n] = *(const bf16x8*)&Bs[0][wc * 64 + n * 16 + fr][fg * 8];
        if constexpr (SPLIT) {
            #pragma unroll
            for (int m = 0; m < 4; m++) afl[m] = *(const bf16x8*)&As[1][wr * 64 + m * 16 + fr][fg * 8];
            #pragma unroll
            for (int n = 0; n < 4; n++) bfl[n] = *(const bf16x8*)&Bs[1][wc * 64 + n * 16 + fr][fg * 8];
        }
        #pragma unroll
        for (int m = 0; m < 4; m++)
            #pragma unroll
            for (int n = 0; n < 4; n++) {
                acc[m][n] = MFMA_BF16(afh[m], bfh[n], acc[m][n]);
                if constexpr (SPLIT) {
                    acc[m][n] = MFMA_BF16(afl[m], bfh[n], acc[m][n]);
                    acc[m][n] = MFMA_BF16(afh[m], bfl[n], acc[m][n]);
                }
            }
    }

    // epilogue: D layout row = fg*4 + j, col = fr  (per 16x16 fragment)
    #pragma unroll
    for (int m = 0; m < 4; m++) {
        #pragma unroll
        for (int n = 0; n < 4; n++) {
            #pragma unroll
            for (int j = 0; j < 4; j++) {
                int row = rA0 + wr * 64 + m * 16 + fg * 4 + j;
                int col = cB0 + wc * 64 + n * 16 + fr;
                float v = acc[m][n][j];
                if constexpr (EPI == 1 || EPI == 2) v += bias[col];
                if constexpr (EPI == 1) v = fmaxf(v, 0.f);
                if constexpr (EPI == 0 || EPI == 1) {
                    Cb[(size_t)row * N + col] = f2bf(v);
                } else if constexpr (EPI == 2) {
                    Cf[(size_t)row * N + col] = v;
                } else {  // QKV scatter: col = t*512 + h*64 + k ; row = b*2048 + tt
                    int t = col >> 9, h = (col >> 6) & 7, k = col & 63;
                    int b = row >> 11, tt = row & 2047;
                    size_t di = ((size_t)((b << 3) + h) * 2048 + tt) * 64 + k;
                    unsigned short hh = f2bf(v);
                    if (t == 0)      { Qh[di] = hh; Ql[di] = f2bf(v - bf2f(hh)); }
                    else if (t == 1) { Kh[di] = hh; Kl[di] = f2bf(v - bf2f(hh)); }
                    else             { Vo[di] = hh; }
                }
            }
        }
    }
}

// ---------------- flash attention (split-precision QK^T) ----------------
// grid.x = B*H*(T/64); 4 waves, each owns 16 q-rows; 32 keys per iteration
__global__ __launch_bounds__(256)
void attn_kernel(const unsigned short* __restrict__ Qh, const unsigned short* __restrict__ Ql,
                 const unsigned short* __restrict__ Kh, const unsigned short* __restrict__ Kl,
                 const unsigned short* __restrict__ Vb, unsigned short* __restrict__ Ob)
{
    constexpr int T = 2048;
    __shared__ __align__(16) unsigned short Ksh[32][72];     // K hi rows, padded
    __shared__ __align__(16) unsigned short Ksl[32][72];     // K lo rows
    __shared__ __align__(16) unsigned short Vts[64][40];     // V^T: [v][s], padded
    __shared__ __align__(16) unsigned short Plds[4][16][40]; // per-wave P, [q][s], padded

    const int tid = threadIdx.x, lane = tid & 63, wave = tid >> 6;
    const int bh = blockIdx.x >> 5;
    const int q0 = (blockIdx.x & 31) * 64;
    const size_t base = (size_t)bh * T * 64;
    const int fr = lane & 15, fg = lane >> 4;

    const size_t qoff = base + (size_t)(q0 + wave * 16 + fr) * 64;
    bf16x8 aq0h = *(const bf16x8*)&Qh[qoff + fg * 8];
    bf16x8 aq1h = *(const bf16x8*)&Qh[qoff + 32 + fg * 8];
    bf16x8 aq0l = *(const bf16x8*)&Ql[qoff + fg * 8];
    bf16x8 aq1l = *(const bf16x8*)&Ql[qoff + 32 + fg * 8];

    f32x4 o[4];
    #pragma unroll
    for (int n = 0; n < 4; n++) o[n] = f32x4{0.f, 0.f, 0.f, 0.f};
    float mrun[4] = {-1e30f, -1e30f, -1e30f, -1e30f};
    float lrun[4] = {0.f, 0.f, 0.f, 0.f};

    for (int s0 = 0; s0 < T; s0 += 32) {
        __syncthreads();
        {   // stage K hi/lo blocks (32 x 64) + V^T (64 x 32)
            int srow = tid >> 3, k8 = (tid & 7) << 3;
            size_t g = base + (size_t)(s0 + srow) * 64 + k8;
            *(uint4*)&Ksh[srow][k8] = *(const uint4*)&Kh[g];
            *(uint4*)&Ksl[srow][k8] = *(const uint4*)&Kl[g];
            bf16x8 vv = *(const bf16x8*)&Vb[g];
            #pragma unroll
            for (int j = 0; j < 8; j++) Vts[k8 + j][srow] = (unsigned short)vv[j];
        }
        __syncthreads();

        // scores: S = Q (16x64) . K^T (64x32), split hi/lo -> two 16x16 fragments
        f32x4 sc[2];
        #pragma unroll
        for (int c = 0; c < 2; c++) {
            bf16x8 b0h = *(const bf16x8*)&Ksh[c * 16 + fr][fg * 8];
            bf16x8 b1h = *(const bf16x8*)&Ksh[c * 16 + fr][32 + fg * 8];
            bf16x8 b0l = *(const bf16x8*)&Ksl[c * 16 + fr][fg * 8];
            bf16x8 b1l = *(const bf16x8*)&Ksl[c * 16 + fr][32 + fg * 8];
            f32x4 z = f32x4{0.f, 0.f, 0.f, 0.f};
            z = MFMA_BF16(aq0h, b0h, z);
            z = MFMA_BF16(aq0l, b0h, z);
            z = MFMA_BF16(aq0h, b0l, z);
            z = MFMA_BF16(aq1h, b1h, z);
            z = MFMA_BF16(aq1l, b1h, z);
            z = MFMA_BF16(aq1h, b1l, z);
            sc[c] = z * 0.125f;   // 1/sqrt(64)
        }

        // online softmax (rows live across the 16-lane group; 4 rows/lane)
        float alpha[4];
        #pragma unroll
        for (int r = 0; r < 4; r++) {
            float v = fmaxf(sc[0][r], sc[1][r]);
            v = fmaxf(v, __shfl_xor(v, 1)); v = fmaxf(v, __shfl_xor(v, 2));
            v = fmaxf(v, __shfl_xor(v, 4)); v = fmaxf(v, __shfl_xor(v, 8));
            float mn = fmaxf(mrun[r], v);
            alpha[r] = __expf(mrun[r] - mn);
            mrun[r] = mn;
        }
        float rs[4] = {0.f, 0.f, 0.f, 0.f};
        #pragma unroll
        for (int c = 0; c < 2; c++)
            #pragma unroll
            for (int r = 0; r < 4; r++) {
                float p = __expf(sc[c][r] - mrun[r]);
                sc[c][r] = p;
                rs[r] += p;
            }
        #pragma unroll
        for (int r = 0; r < 4; r++) {
            float t = rs[r];
            t += __shfl_xor(t, 1); t += __shfl_xor(t, 2);
            t += __shfl_xor(t, 4); t += __shfl_xor(t, 8);
            lrun[r] = lrun[r] * alpha[r] + t;
            #pragma unroll
            for (int n = 0; n < 4; n++) o[n][r] *= alpha[r];
        }

        // P (D-layout) -> LDS -> A-layout for PV
        #pragma unroll
        for (int c = 0; c < 2; c++)
            #pragma unroll
            for (int r = 0; r < 4; r++)
                Plds[wave][fg * 4 + r][c * 16 + fr] = f2bf(sc[c][r]);
        __syncthreads();

        bf16x8 pa = *(const bf16x8*)&Plds[wave][fr][fg * 8];
        #pragma unroll
        for (int n = 0; n < 4; n++) {
            bf16x8 bv = *(const bf16x8*)&Vts[n * 16 + fr][fg * 8];
            o[n] = MFMA_BF16(pa, bv, o[n]);
        }
    }

    #pragma unroll
    for (int r = 0; r < 4; r++) {
        float inv = 1.0f / lrun[r];
        #pragma unroll
        for (int n = 0; n < 4; n++) o[n][r] *= inv;
    }
    #pragma unroll
    for (int n = 0; n < 4; n++)
        #pragma unroll
        for (int r = 0; r < 4; r++)
            Ob[base + (size_t)(q0 + wave * 16 + fg * 4 + r) * 64 + n * 16 + fr] = f2bf(o[n][r]);
}

// ---------------- launch ----------------
extern "C" void kernel_launch(void* const* d_in, const int* in_sizes, int n_in,
                              void* d_out, int out_size, void* d_ws, size_t ws_size,
                              hipStream_t stream)
{
    const float* x  = (const float*)d_in[0];
    const float* Wq = (const float*)d_in[1];
    const float* Wk = (const float*)d_in[2];
    const float* Wv = (const float*)d_in[3];
    const float* Wo = (const float*)d_in[4];
    const float* W1 = (const float*)d_in[5];
    const float* b1 = (const float*)d_in[6];
    const float* W2 = (const float*)d_in[7];
    const float* b2 = (const float*)d_in[8];
    float* out = (float*)d_out;

    char* ws = (char*)d_ws;
    size_t off = 0;
    auto alloc = [&](size_t bytes) -> void* {
        void* p = ws + off; off += (bytes + 255) & ~(size_t)255; return p;
    };
    unsigned short* wqkvTh = (unsigned short*)alloc(1536ull * 512 * 2);
    unsigned short* wqkvTl = (unsigned short*)alloc(1536ull * 512 * 2);
    unsigned short* woT    = (unsigned short*)alloc(512ull * 512 * 2);
    unsigned short* w1T    = (unsigned short*)alloc(2048ull * 512 * 2);
    unsigned short* w2T    = (unsigned short*)alloc(512ull * 2048 * 2);
    unsigned short* Qhb    = (unsigned short*)alloc(8192ull * 512 * 2);  // contiguous run:
    unsigned short* Qlb    = (unsigned short*)alloc(8192ull * 512 * 2);  // Qh,Ql,Kh,Kl = 32MB
    unsigned short* Khb    = (unsigned short*)alloc(8192ull * 512 * 2);  // reused as hb later
    unsigned short* Klb    = (unsigned short*)alloc(8192ull * 512 * 2);
    unsigned short* Vbuf   = (unsigned short*)alloc(8192ull * 512 * 2);
    unsigned short* xh     = (unsigned short*)alloc(8192ull * 512 * 2);
    unsigned short* xl     = (unsigned short*)alloc(8192ull * 512 * 2);
    // aliases (lifetimes do not overlap):
    unsigned short* attb = xh;   // attn out, after QKV GEMM consumed xh/xl
    unsigned short* outb = xl;   // Wo out
    unsigned short* hb   = Qhb;  // FF1 out (32MB across Qh..Kl), after attention

    k_cvt_split<<<8192 * 512 / 256, 256, 0, stream>>>(x, xh, xl, 8192 * 512);
    k_prep_qkvT<<<1536 * 512 / 256, 256, 0, stream>>>(Wq, Wk, Wv, wqkvTh, wqkvTl);
    k_prep_T<<<512 * 512 / 256, 256, 0, stream>>>(Wo, woT, 512, 512);
    k_prep_T<<<2048 * 512 / 256, 256, 0, stream>>>(W1, w1T, 512, 2048);
    k_prep_T<<<512 * 2048 / 256, 256, 0, stream>>>(W2, w2T, 2048, 512);

    // QKV projection (split precision): (8192x512) @ (512x1536) -> Q/K split + V
    gemm_bt<3, true><<<dim3(1536 / 128, 8192 / 128), 256, 0, stream>>>(
        xh, xl, wqkvTh, wqkvTl, 8192, 1536, 512, nullptr,
        nullptr, nullptr, Qhb, Qlb, Khb, Klb, Vbuf);

    // attention -> attb (B,H,T,64) flat == (B,T',512) for the Wo GEMM (raw reshape)
    attn_kernel<<<4 * 8 * (2048 / 64), 256, 0, stream>>>(Qhb, Qlb, Khb, Klb, Vbuf, attb);

    // out = att' @ Wo
    gemm_bt<0, false><<<dim3(512 / 128, 8192 / 128), 256, 0, stream>>>(
        attb, nullptr, woT, nullptr, 8192, 512, 512, nullptr,
        outb, nullptr, nullptr, nullptr, nullptr, nullptr, nullptr);

    // h = relu(out @ W1 + b1)
    gemm_bt<1, false><<<dim3(2048 / 128, 8192 / 128), 256, 0, stream>>>(
        outb, nullptr, w1T, nullptr, 8192, 2048, 512, b1,
        hb, nullptr, nullptr, nullptr, nullptr, nullptr, nullptr);

    // y = h @ W2 + b2  (f32 output)
    gemm_bt<2, false><<<dim3(512 / 128, 8192 / 128), 256, 0, stream>>>(
        hb, nullptr, w2T, nullptr, 8192, 512, 2048, b2,
        nullptr, out, nullptr, nullptr, nullptr, nullptr, nullptr);
}

// Round 3
// 404.938 us; speedup vs baseline: 1.2216x; 1.2216x over previous
//
#include <hip/hip_runtime.h>
#include <hip/hip_bf16.h>

typedef short bf16x8 __attribute__((ext_vector_type(8)));
typedef float f32x4 __attribute__((ext_vector_type(4)));

#define MFMA_BF16(A,B,C) __builtin_amdgcn_mfma_f32_16x16x32_bf16((A),(B),(C),0,0,0)

__device__ __forceinline__ unsigned short f2bf(float f){
    union { float f; unsigned u; } v; v.f = f;
    unsigned r = v.u + 0x7fffu + ((v.u >> 16) & 1u);
    return (unsigned short)(r >> 16);
}
__device__ __forceinline__ float bf2f(unsigned short h){
    union { unsigned u; float f; } v; v.u = ((unsigned)h) << 16; return v.f;
}

// ---------------- prep kernels ----------------
// split cast: hi = bf16(v), lo = bf16(v - hi)
__global__ __launch_bounds__(256) void k_cvt_split(const float* __restrict__ in,
                                                   unsigned short* __restrict__ hi,
                                                   unsigned short* __restrict__ lo, int n){
    int i = blockIdx.x * 256 + threadIdx.x;
    if (i < n) {
        float v = in[i];
        unsigned short h = f2bf(v);
        hi[i] = h;
        lo[i] = f2bf(v - bf2f(h));
    }
}

// Fused QK weight, transposed, split hi/lo: row c = t*512 + h*64 + k (t: 0=Q,1=K)
__global__ __launch_bounds__(256) void k_prep_qkT(const float* __restrict__ Wq,
                                                  const float* __restrict__ Wk,
                                                  unsigned short* __restrict__ hi,
                                                  unsigned short* __restrict__ lo){
    int idx = blockIdx.x * 256 + threadIdx.x;   // [0, 1024*512)
    int c = idx >> 9, d = idx & 511;
    int t = c >> 9, rem = c & 511;
    int h = rem >> 6, k = rem & 63;
    const float* W = (t == 0) ? Wq : Wk;
    float v = W[(h * 512 + d) * 64 + k];
    unsigned short hh = f2bf(v);
    hi[idx] = hh;
    lo[idx] = f2bf(v - bf2f(hh));
}

// WvT: row hk = h*64+k, col d:  WvT[hk][d] = Wv[h][d][k]
__global__ __launch_bounds__(256) void k_prep_wvT(const float* __restrict__ Wv,
                                                  unsigned short* __restrict__ out){
    int idx = blockIdx.x * 256 + threadIdx.x;   // [0, 512*512)
    int row = idx >> 9, d = idx & 511;
    int h = row >> 6, k = row & 63;
    out[idx] = f2bf(Wv[(h * 512 + d) * 64 + k]);
}

// Generic transpose+cast: W is (D,N) row-major f32; out is (N,D) row-major bf16
__global__ __launch_bounds__(256) void k_prep_T(const float* __restrict__ W,
                                                unsigned short* __restrict__ out, int D, int N){
    int idx = blockIdx.x * 256 + threadIdx.x;   // [0, N*D)
    int n = idx / D, d = idx - n * D;
    out[idx] = f2bf(W[d * N + n]);
}

// ---------------- GEMM: C = A(MxK) * Bt(NxK)^T ----------------
// EPI: 0 = bf16 out, 1 = bias+relu bf16 out, 2 = bias f32 out,
//      3 = QK split scatter, 4 = Vt scatter (row=hk, col=bt -> Vt[bh][k][t])
template<int EPI, bool SPLIT>
__global__ __launch_bounds__(256)
void gemm_bt(const unsigned short* __restrict__ Ah, const unsigned short* __restrict__ Al,
             const unsigned short* __restrict__ Bh, const unsigned short* __restrict__ Bl,
             int M, int N, int K, const float* __restrict__ bias,
             unsigned short* __restrict__ Cb, float* __restrict__ Cf,
             unsigned short* __restrict__ Qh, unsigned short* __restrict__ Ql,
             unsigned short* __restrict__ Kh, unsigned short* __restrict__ Kl,
             unsigned short* __restrict__ Vo)
{
    constexpr int BK = 32, LDP = 40;            // pad 32->40 elems: 2-way max bank conflict
    constexpr int NS = SPLIT ? 2 : 1;
    __shared__ __align__(16) unsigned short As[NS][128][LDP];
    __shared__ __align__(16) unsigned short Bs[NS][128][LDP];

    const int tid = threadIdx.x, lane = tid & 63, wave = tid >> 6;
    const int wr = wave >> 1, wc = wave & 1;
    const int bm = blockIdx.y, bn = blockIdx.x;
    const int rA0 = bm * 128, cB0 = bn * 128;
    const int fr = lane & 15, fg = lane >> 4;

    f32x4 acc[4][4];
    #pragma unroll
    for (int m = 0; m < 4; m++)
        #pragma unroll
        for (int n = 0; n < 4; n++)
            acc[m][n] = f32x4{0.f, 0.f, 0.f, 0.f};

    for (int kt = 0; kt < K; kt += BK) {
        __syncthreads();
        #pragma unroll
        for (int q = 0; q < 2; q++) {
            int ch = tid + q * 256;             // 512 chunks of 8 bf16
            int r = ch >> 2, kk = (ch & 3) << 3;
            size_t ga = (size_t)(rA0 + r) * K + kt + kk;
            size_t gb = (size_t)(cB0 + r) * K + kt + kk;
            *(uint4*)&As[0][r][kk] = *(const uint4*)&Ah[ga];
            *(uint4*)&Bs[0][r][kk] = *(const uint4*)&Bh[gb];
            if constexpr (SPLIT) {
                *(uint4*)&As[1][r][kk] = *(const uint4*)&Al[ga];
                *(uint4*)&Bs[1][r][kk] = *(const uint4*)&Bl[gb];
            }
        }
        __syncthreads();

        bf16x8 afh[4], bfh[4], afl[4], bfl[4];
        #pragma unroll
        for (int m = 0; m < 4; m++) afh[m] = *(const bf16x8*)&As[0][wr * 64 + m * 16 + fr][fg * 8];
        #pragma unroll
        for (int n = 0; n < 4; n++) bfh[n] = *(const bf16x8*)&Bs[0][wc * 64 + n * 16 + fr][fg * 8];
        if constexpr (SPLIT) {
            #pragma unroll
            for (int m = 0; m < 4; m++) afl[m] = *(const bf16x8*)&As[1][wr * 64 + m * 16 + fr][fg * 8];
            #pragma unroll
            for (int n = 0; n < 4; n++) bfl[n] = *(const bf16x8*)&Bs[1][wc * 64 + n * 16 + fr][fg * 8];
        }
        #pragma unroll
        for (int m = 0; m < 4; m++)
            #pragma unroll
            for (int n = 0; n < 4; n++) {
                acc[m][n] = MFMA_BF16(afh[m], bfh[n], acc[m][n]);
                if constexpr (SPLIT) {
                    acc[m][n] = MFMA_BF16(afl[m], bfh[n], acc[m][n]);
                    acc[m][n] = MFMA_BF16(afh[m], bfl[n], acc[m][n]);
                }
            }
    }

    // epilogue: D layout row = fg*4 + j, col = fr  (per 16x16 fragment)
    #pragma unroll
    for (int m = 0; m < 4; m++) {
        #pragma unroll
        for (int n = 0; n < 4; n++) {
            #pragma unroll
            for (int j = 0; j < 4; j++) {
                int row = rA0 + wr * 64 + m * 16 + fg * 4 + j;
                int col = cB0 + wc * 64 + n * 16 + fr;
                float v = acc[m][n][j];
                if constexpr (EPI == 1 || EPI == 2) v += bias[col];
                if constexpr (EPI == 1) v = fmaxf(v, 0.f);
                if constexpr (EPI == 0 || EPI == 1) {
                    Cb[(size_t)row * N + col] = f2bf(v);
                } else if constexpr (EPI == 2) {
                    Cf[(size_t)row * N + col] = v;
                } else if constexpr (EPI == 3) {
                    // col = t*512 + h*64 + k (t: 0=Q,1=K); row = b*2048 + tt
                    int t = col >> 9, h = (col >> 6) & 7, k = col & 63;
                    int b = row >> 11, tt = row & 2047;
                    size_t di = ((size_t)((b << 3) + h) * 2048 + tt) * 64 + k;
                    unsigned short hh = f2bf(v);
                    if (t == 0) { Qh[di] = hh; Ql[di] = f2bf(v - bf2f(hh)); }
                    else        { Kh[di] = hh; Kl[di] = f2bf(v - bf2f(hh)); }
                } else {
                    // EPI==4: row = h*64+k, col = b*2048+t -> Vt[((b*8+h)*64+k)*2048 + t]
                    int h = row >> 6, k = row & 63;
                    int b = col >> 11, tt = col & 2047;
                    Vo[(((size_t)(b * 8 + h) * 64 + k) << 11) + tt] = f2bf(v);
                }
            }
        }
    }
}

// ---------------- flash attention (split-precision QK^T, pre-transposed V) --
// grid.x = B*H*(T/64); 4 waves, each owns 16 q-rows; 64 keys per iteration
__global__ __launch_bounds__(256)
void attn_kernel(const unsigned short* __restrict__ Qh, const unsigned short* __restrict__ Ql,
                 const unsigned short* __restrict__ Kh, const unsigned short* __restrict__ Kl,
                 const unsigned short* __restrict__ Vt, unsigned short* __restrict__ Ob)
{
    constexpr int T = 2048;
    __shared__ __align__(16) unsigned short Ksh[64][72];     // K hi rows (s-major), padded
    __shared__ __align__(16) unsigned short Ksl[64][72];     // K lo rows
    __shared__ __align__(16) unsigned short Vts[64 * 64];    // [v][s], XOR-swizzled 16B slots
    __shared__ __align__(16) unsigned short Plds[4][16][72]; // per-wave P, [q][s]

    const int tid = threadIdx.x, lane = tid & 63, wave = tid >> 6;
    const int bh = blockIdx.x >> 5;
    const int q0 = (blockIdx.x & 31) * 64;
    const size_t base = (size_t)bh * T * 64;
    const int fr = lane & 15, fg = lane >> 4;

    const size_t qoff = base + (size_t)(q0 + wave * 16 + fr) * 64;
    bf16x8 aq0h = *(const bf16x8*)&Qh[qoff + fg * 8];
    bf16x8 aq1h = *(const bf16x8*)&Qh[qoff + 32 + fg * 8];
    bf16x8 aq0l = *(const bf16x8*)&Ql[qoff + fg * 8];
    bf16x8 aq1l = *(const bf16x8*)&Ql[qoff + 32 + fg * 8];

    f32x4 o[4];
    #pragma unroll
    for (int n = 0; n < 4; n++) o[n] = f32x4{0.f, 0.f, 0.f, 0.f};
    float mrun[4] = {-1e30f, -1e30f, -1e30f, -1e30f};
    float lrun[4] = {0.f, 0.f, 0.f, 0.f};

    const int srow = tid >> 3, c8 = (tid & 7) << 3;
    char* vbase = (char*)Vts;

    for (int s0 = 0; s0 < T; s0 += 64) {
        __syncthreads();
        #pragma unroll
        for (int it = 0; it < 2; it++) {
            int r = srow + it * 32;
            size_t g = base + (size_t)(s0 + r) * 64 + c8;
            *(uint4*)&Ksh[r][c8] = *(const uint4*)&Kh[g];
            *(uint4*)&Ksl[r][c8] = *(const uint4*)&Kl[g];
            // V^T tile: rows = v, cols = s; global Vt[(bh*64+v)*2048 + s0 + c8]
            uint4 vv = *(const uint4*)&Vt[((size_t)(bh * 64 + r) << 11) + s0 + c8];
            int byteoff = r * 128 + ((c8 * 2) ^ ((r & 7) << 4));
            *(uint4*)(vbase + byteoff) = vv;
        }
        __syncthreads();

        // scores: S = Q (16x64) . K^T (64x64), split hi/lo -> four 16x16 fragments
        f32x4 sc[4];
        #pragma unroll
        for (int c = 0; c < 4; c++) {
            bf16x8 b0h = *(const bf16x8*)&Ksh[c * 16 + fr][fg * 8];
            bf16x8 b1h = *(const bf16x8*)&Ksh[c * 16 + fr][32 + fg * 8];
            bf16x8 b0l = *(const bf16x8*)&Ksl[c * 16 + fr][fg * 8];
            bf16x8 b1l = *(const bf16x8*)&Ksl[c * 16 + fr][32 + fg * 8];
            f32x4 z = f32x4{0.f, 0.f, 0.f, 0.f};
            z = MFMA_BF16(aq0h, b0h, z);
            z = MFMA_BF16(aq0l, b0h, z);
            z = MFMA_BF16(aq0h, b0l, z);
            z = MFMA_BF16(aq1h, b1h, z);
            z = MFMA_BF16(aq1l, b1h, z);
            z = MFMA_BF16(aq1h, b1l, z);
            sc[c] = z * 0.125f;   // 1/sqrt(64)
        }

        // online softmax (rows live across the 16-lane group; 4 rows/lane)
        float alpha[4];
        #pragma unroll
        for (int r = 0; r < 4; r++) {
            float v = fmaxf(fmaxf(sc[0][r], sc[1][r]), fmaxf(sc[2][r], sc[3][r]));
            v = fmaxf(v, __shfl_xor(v, 1)); v = fmaxf(v, __shfl_xor(v, 2));
            v = fmaxf(v, __shfl_xor(v, 4)); v = fmaxf(v, __shfl_xor(v, 8));
            float mn = fmaxf(mrun[r], v);
            alpha[r] = __expf(mrun[r] - mn);
            mrun[r] = mn;
        }
        float rs[4] = {0.f, 0.f, 0.f, 0.f};
        #pragma unroll
        for (int c = 0; c < 4; c++)
            #pragma unroll
            for (int r = 0; r < 4; r++) {
                float p = __expf(sc[c][r] - mrun[r]);
                sc[c][r] = p;
                rs[r] += p;
            }
        #pragma unroll
        for (int r = 0; r < 4; r++) {
            float t = rs[r];
            t += __shfl_xor(t, 1); t += __shfl_xor(t, 2);
            t += __shfl_xor(t, 4); t += __shfl_xor(t, 8);
            lrun[r] = lrun[r] * alpha[r] + t;
            #pragma unroll
            for (int n = 0; n < 4; n++) o[n][r] *= alpha[r];
        }

        // P (D-layout) -> LDS -> A-layout for PV
        #pragma unroll
        for (int c = 0; c < 4; c++)
            #pragma unroll
            for (int r = 0; r < 4; r++)
                Plds[wave][fg * 4 + r][c * 16 + fr] = f2bf(sc[c][r]);
        __syncthreads();

        bf16x8 pa0 = *(const bf16x8*)&Plds[wave][fr][fg * 8];
        bf16x8 pa1 = *(const bf16x8*)&Plds[wave][fr][32 + fg * 8];
        #pragma unroll
        for (int n = 0; n < 4; n++) {
            int row = n * 16 + fr;
            bf16x8 bv0 = *(const bf16x8*)(vbase + row * 128 + ((fg * 16)      ^ ((row & 7) << 4)));
            bf16x8 bv1 = *(const bf16x8*)(vbase + row * 128 + ((64 + fg * 16) ^ ((row & 7) << 4)));
            o[n] = MFMA_BF16(pa0, bv0, o[n]);
            o[n] = MFMA_BF16(pa1, bv1, o[n]);
        }
    }

    #pragma unroll
    for (int r = 0; r < 4; r++) {
        float inv = 1.0f / lrun[r];
        #pragma unroll
        for (int n = 0; n < 4; n++) o[n][r] *= inv;
    }
    #pragma unroll
    for (int n = 0; n < 4; n++)
        #pragma unroll
        for (int r = 0; r < 4; r++)
            Ob[base + (size_t)(q0 + wave * 16 + fg * 4 + r) * 64 + n * 16 + fr] = f2bf(o[n][r]);
}

// ---------------- launch ----------------
extern "C" void kernel_launch(void* const* d_in, const int* in_sizes, int n_in,
                              void* d_out, int out_size, void* d_ws, size_t ws_size,
                              hipStream_t stream)
{
    const float* x  = (const float*)d_in[0];
    const float* Wq = (const float*)d_in[1];
    const float* Wk = (const float*)d_in[2];
    const float* Wv = (const float*)d_in[3];
    const float* Wo = (const float*)d_in[4];
    const float* W1 = (const float*)d_in[5];
    const float* b1 = (const float*)d_in[6];
    const float* W2 = (const float*)d_in[7];
    const float* b2 = (const float*)d_in[8];
    float* out = (float*)d_out;

    char* ws = (char*)d_ws;
    size_t off = 0;
    auto alloc = [&](size_t bytes) -> void* {
        void* p = ws + off; off += (bytes + 255) & ~(size_t)255; return p;
    };
    unsigned short* wqkTh = (unsigned short*)alloc(1024ull * 512 * 2);
    unsigned short* wqkTl = (unsigned short*)alloc(1024ull * 512 * 2);
    unsigned short* wvT   = (unsigned short*)alloc(512ull * 512 * 2);
    unsigned short* woT   = (unsigned short*)alloc(512ull * 512 * 2);
    unsigned short* w1T   = (unsigned short*)alloc(2048ull * 512 * 2);
    unsigned short* w2T   = (unsigned short*)alloc(512ull * 2048 * 2);
    unsigned short* Qhb   = (unsigned short*)alloc(8192ull * 512 * 2);  // Qh,Ql,Kh,Kl are
    unsigned short* Qlb   = (unsigned short*)alloc(8192ull * 512 * 2);  // contiguous 32MB,
    unsigned short* Khb   = (unsigned short*)alloc(8192ull * 512 * 2);  // reused as hb later
    unsigned short* Klb   = (unsigned short*)alloc(8192ull * 512 * 2);
    unsigned short* Vtb   = (unsigned short*)alloc(8192ull * 512 * 2);  // (b,h,k,t)
    unsigned short* xh    = (unsigned short*)alloc(8192ull * 512 * 2);
    unsigned short* xl    = (unsigned short*)alloc(8192ull * 512 * 2);
    // aliases (lifetimes do not overlap):
    unsigned short* attb = xh;   // attn out, after QK/Vt GEMMs consumed xh/xl
    unsigned short* outb = xl;   // Wo out
    unsigned short* hb   = Qhb;  // FF1 out (32MB across Qh..Kl), after attention

    k_cvt_split<<<8192 * 512 / 256, 256, 0, stream>>>(x, xh, xl, 8192 * 512);
    k_prep_qkT<<<1024 * 512 / 256, 256, 0, stream>>>(Wq, Wk, wqkTh, wqkTl);
    k_prep_wvT<<<512 * 512 / 256, 256, 0, stream>>>(Wv, wvT);
    k_prep_T<<<512 * 512 / 256, 256, 0, stream>>>(Wo, woT, 512, 512);
    k_prep_T<<<2048 * 512 / 256, 256, 0, stream>>>(W1, w1T, 512, 2048);
    k_prep_T<<<512 * 2048 / 256, 256, 0, stream>>>(W2, w2T, 2048, 512);

    // QK projection (split precision): (8192x512) @ (512x1024) -> Q/K hi+lo
    gemm_bt<3, true><<<dim3(1024 / 128, 8192 / 128), 256, 0, stream>>>(
        xh, xl, wqkTh, wqkTl, 8192, 1024, 512, nullptr,
        nullptr, nullptr, Qhb, Qlb, Khb, Klb, nullptr);

    // V^T projection: rows = (h,k) 512, cols = (b,t) 8192 -> Vt[(b,h),k,t]
    gemm_bt<4, false><<<dim3(8192 / 128, 512 / 128), 256, 0, stream>>>(
        wvT, nullptr, xh, nullptr, 512, 8192, 512, nullptr,
        nullptr, nullptr, nullptr, nullptr, nullptr, nullptr, Vtb);

    // attention -> attb (B,H,T,64) flat == (B,T',512) for the Wo GEMM (raw reshape)
    attn_kernel<<<4 * 8 * (2048 / 64), 256, 0, stream>>>(Qhb, Qlb, Khb, Klb, Vtb, attb);

    // out = att' @ Wo
    gemm_bt<0, false><<<dim3(512 / 128, 8192 / 128), 256, 0, stream>>>(
        attb, nullptr, woT, nullptr, 8192, 512, 512, nullptr,
        outb, nullptr, nullptr, nullptr, nullptr, nullptr, nullptr);

    // h = relu(out @ W1 + b1)
    gemm_bt<1, false><<<dim3(2048 / 128, 8192 / 128), 256, 0, stream>>>(
        outb, nullptr, w1T, nullptr, 8192, 2048, 512, b1,
        hb, nullptr, nullptr, nullptr, nullptr, nullptr, nullptr);

    // y = h @ W2 + b2  (f32 output)
    gemm_bt<2, false><<<dim3(512 / 128, 8192 / 128), 256, 0, stream>>>(
        hb, nullptr, w2T, nullptr, 8192, 512, 2048, b2,
        nullptr, out, nullptr, nullptr, nullptr, nullptr, nullptr);
}

// Round 4
// 388.763 us; speedup vs baseline: 1.2724x; 1.0416x over previous
//
#include <hip/hip_runtime.h>
#include <hip/hip_bf16.h>

typedef short bf16x8 __attribute__((ext_vector_type(8)));
typedef float f32x4 __attribute__((ext_vector_type(4)));

#define MFMA_BF16(A,B,C) __builtin_amdgcn_mfma_f32_16x16x32_bf16((A),(B),(C),0,0,0)

__device__ __forceinline__ unsigned short f2bf(float f){
    union { float f; unsigned u; } v; v.f = f;
    unsigned r = v.u + 0x7fffu + ((v.u >> 16) & 1u);
    return (unsigned short)(r >> 16);
}
__device__ __forceinline__ float bf2f(unsigned short h){
    union { unsigned u; float f; } v; v.u = ((unsigned)h) << 16; return v.f;
}

// async global->LDS, 16B per lane; lds dest = wave-uniform base + lane*16
__device__ __forceinline__ void gl_lds16(const unsigned short* g, void* l){
    __builtin_amdgcn_global_load_lds(
        (const __attribute__((address_space(1))) unsigned int*)g,
        (__attribute__((address_space(3))) unsigned int*)l, 16, 0, 0);
}

// ---------------- prep kernels ----------------
// vectorized split cast: hi = bf16(v), lo = bf16(v - hi); 4 elems/thread
__global__ __launch_bounds__(256) void k_cvt_split(const float4* __restrict__ in,
                                                   ushort4* __restrict__ hi,
                                                   ushort4* __restrict__ lo, int n4){
    int i = blockIdx.x * 256 + threadIdx.x;
    if (i < n4) {
        float4 v = in[i];
        ushort4 h, l;
        h.x = f2bf(v.x); l.x = f2bf(v.x - bf2f(h.x));
        h.y = f2bf(v.y); l.y = f2bf(v.y - bf2f(h.y));
        h.z = f2bf(v.z); l.z = f2bf(v.z - bf2f(h.z));
        h.w = f2bf(v.w); l.w = f2bf(v.w - bf2f(h.w));
        hi[i] = h; lo[i] = l;
    }
}

// tiled transpose+cast (+optional split): in f32 (R x C) per head -> out bf16 (C x R)
// out element (c,r) at outHi[outBase + z*C*R + c*R + r]
__global__ __launch_bounds__(256)
void k_transT(const float* __restrict__ in, long inHeadStride,
              unsigned short* __restrict__ hi, unsigned short* __restrict__ lo,
              int R, int C, long outBase){
    __shared__ float t[32][33];
    const float* src = in + (size_t)blockIdx.z * inHeadStride;
    int c0 = blockIdx.x * 32, r0 = blockIdx.y * 32;
    int tx = threadIdx.x & 31, ty = threadIdx.x >> 5;   // 32 x 8
    #pragma unroll
    for (int i = 0; i < 4; i++)
        t[ty + i * 8][tx] = src[(size_t)(r0 + ty + i * 8) * C + c0 + tx];
    __syncthreads();
    size_t ob = (size_t)outBase + (size_t)blockIdx.z * C * R;
    #pragma unroll
    for (int i = 0; i < 4; i++) {
        int c = c0 + ty + i * 8, r = r0 + tx;
        float v = t[tx][ty + i * 8];
        unsigned short hh = f2bf(v);
        hi[ob + (size_t)c * R + r] = hh;
        if (lo) lo[ob + (size_t)c * R + r] = f2bf(v - bf2f(hh));
    }
}

// ---------------- GEMM: C = A(MxK) * Bt(NxK)^T ----------------
// m97 structure: linear LDS [128][32], global_load_lds width=16, BK=32.
// EPI: 0 = bf16 out, 1 = bias+relu bf16 out, 2 = bias f32 out,
//      3 = QK split scatter, 4 = Vt scatter (row=hk, col=bt -> Vt[bh][k][t])
template<int EPI, bool SPLIT>
__global__ __launch_bounds__(256)
void gemm_bt(const unsigned short* __restrict__ Ah, const unsigned short* __restrict__ Al,
             const unsigned short* __restrict__ Bh, const unsigned short* __restrict__ Bl,
             int M, int N, int K, const float* __restrict__ bias,
             unsigned short* __restrict__ Cb, float* __restrict__ Cf,
             unsigned short* __restrict__ Qh, unsigned short* __restrict__ Ql,
             unsigned short* __restrict__ Kh, unsigned short* __restrict__ Kl,
             unsigned short* __restrict__ Vo)
{
    constexpr int BK = 32;
    constexpr int NS = SPLIT ? 2 : 1;
    __shared__ __align__(16) unsigned short As[NS][128][BK];
    __shared__ __align__(16) unsigned short Bs[NS][128][BK];

    const int tid = threadIdx.x, lane = tid & 63, wave = tid >> 6;
    const int wr = wave >> 1, wc = wave & 1;
    const int rA0 = blockIdx.y * 128, cB0 = blockIdx.x * 128;
    const int fr = lane & 15, fg = lane >> 4;

    f32x4 acc[4][4];
    #pragma unroll
    for (int m = 0; m < 4; m++)
        #pragma unroll
        for (int n = 0; n < 4; n++)
            acc[m][n] = f32x4{0.f, 0.f, 0.f, 0.f};

    // chunk index for this thread: q*256 + tid; row = ch>>2, col8 = (ch&3)*8
    // LDS byte offset = ch*16 (linear in lane order -> global_load_lds compatible)
    for (int kt = 0; kt < K; kt += BK) {
        __syncthreads();
        #pragma unroll
        for (int q = 0; q < 2; q++) {
            int ch = q * 256 + tid;
            int r = ch >> 2, kk = (ch & 3) << 3;
            size_t ga = (size_t)(rA0 + r) * K + kt + kk;
            size_t gb = (size_t)(cB0 + r) * K + kt + kk;
            char* la0 = (char*)&As[0][0][0] + (q * 256 + wave * 64) * 16;
            char* lb0 = (char*)&Bs[0][0][0] + (q * 256 + wave * 64) * 16;
            gl_lds16(&Ah[ga], la0);
            gl_lds16(&Bh[gb], lb0);
            if constexpr (SPLIT) {
                char* la1 = (char*)&As[1][0][0] + (q * 256 + wave * 64) * 16;
                char* lb1 = (char*)&Bs[1][0][0] + (q * 256 + wave * 64) * 16;
                gl_lds16(&Al[ga], la1);
                gl_lds16(&Bl[gb], lb1);
            }
        }
        __syncthreads();

        bf16x8 afh[4], bfh[4], afl[4], bfl[4];
        #pragma unroll
        for (int m = 0; m < 4; m++) afh[m] = *(const bf16x8*)&As[0][wr * 64 + m * 16 + fr][fg * 8];
        #pragma unroll
        for (int n = 0; n < 4; n++) bfh[n] = *(const bf16x8*)&Bs[0][wc * 64 + n * 16 + fr][fg * 8];
        if constexpr (SPLIT) {
            #pragma unroll
            for (int m = 0; m < 4; m++) afl[m] = *(const bf16x8*)&As[1][wr * 64 + m * 16 + fr][fg * 8];
            #pragma unroll
            for (int n = 0; n < 4; n++) bfl[n] = *(const bf16x8*)&Bs[1][wc * 64 + n * 16 + fr][fg * 8];
        }
        #pragma unroll
        for (int m = 0; m < 4; m++)
            #pragma unroll
            for (int n = 0; n < 4; n++) {
                acc[m][n] = MFMA_BF16(afh[m], bfh[n], acc[m][n]);
                if constexpr (SPLIT) {
                    acc[m][n] = MFMA_BF16(afl[m], bfh[n], acc[m][n]);
                    acc[m][n] = MFMA_BF16(afh[m], bfl[n], acc[m][n]);
                }
            }
    }

    // epilogue: D layout row = fg*4 + j, col = fr  (per 16x16 fragment)
    #pragma unroll
    for (int m = 0; m < 4; m++) {
        #pragma unroll
        for (int n = 0; n < 4; n++) {
            #pragma unroll
            for (int j = 0; j < 4; j++) {
                int row = rA0 + wr * 64 + m * 16 + fg * 4 + j;
                int col = cB0 + wc * 64 + n * 16 + fr;
                float v = acc[m][n][j];
                if constexpr (EPI == 1 || EPI == 2) v += bias[col];
                if constexpr (EPI == 1) v = fmaxf(v, 0.f);
                if constexpr (EPI == 0 || EPI == 1) {
                    Cb[(size_t)row * N + col] = f2bf(v);
                } else if constexpr (EPI == 2) {
                    Cf[(size_t)row * N + col] = v;
                } else if constexpr (EPI == 3) {
                    // col = t*512 + h*64 + k (t: 0=Q,1=K); row = b*2048 + tt
                    int t = col >> 9, h = (col >> 6) & 7, k = col & 63;
                    int b = row >> 11, tt = row & 2047;
                    size_t di = ((size_t)((b << 3) + h) * 2048 + tt) * 64 + k;
                    unsigned short hh = f2bf(v);
                    if (t == 0) { Qh[di] = hh; Ql[di] = f2bf(v - bf2f(hh)); }
                    else        { Kh[di] = hh; Kl[di] = f2bf(v - bf2f(hh)); }
                } else {
                    // EPI==4: row = h*64+k, col = b*2048+t -> Vt[((b*8+h)*64+k)*2048 + t]
                    int h = row >> 6, k = row & 63;
                    int b = col >> 11, tt = col & 2047;
                    Vo[(((size_t)(b * 8 + h) * 64 + k) << 11) + tt] = f2bf(v);
                }
            }
        }
    }
}

// ---------------- flash attention (split-precision QK^T, pre-transposed V) --
// grid.x = B*H*(T/64); 4 waves, each owns 16 q-rows; 64 keys per iteration
__global__ __launch_bounds__(256)
void attn_kernel(const unsigned short* __restrict__ Qh, const unsigned short* __restrict__ Ql,
                 const unsigned short* __restrict__ Kh, const unsigned short* __restrict__ Kl,
                 const unsigned short* __restrict__ Vt, unsigned short* __restrict__ Ob)
{
    constexpr int T = 2048;
    __shared__ __align__(16) unsigned short Ksh[64][72];     // K hi rows (s-major), padded
    __shared__ __align__(16) unsigned short Ksl[64][72];     // K lo rows
    __shared__ __align__(16) unsigned short Vts[64 * 64];    // [v][s], XOR-swizzled 16B slots
    __shared__ __align__(16) unsigned short Plds[4][16][72]; // per-wave P, [q][s]

    const int tid = threadIdx.x, lane = tid & 63, wave = tid >> 6;
    const int bh = blockIdx.x >> 5;
    const int q0 = (blockIdx.x & 31) * 64;
    const size_t base = (size_t)bh * T * 64;
    const int fr = lane & 15, fg = lane >> 4;

    const size_t qoff = base + (size_t)(q0 + wave * 16 + fr) * 64;
    bf16x8 aq0h = *(const bf16x8*)&Qh[qoff + fg * 8];
    bf16x8 aq1h = *(const bf16x8*)&Qh[qoff + 32 + fg * 8];
    bf16x8 aq0l = *(const bf16x8*)&Ql[qoff + fg * 8];
    bf16x8 aq1l = *(const bf16x8*)&Ql[qoff + 32 + fg * 8];

    f32x4 o[4];
    #pragma unroll
    for (int n = 0; n < 4; n++) o[n] = f32x4{0.f, 0.f, 0.f, 0.f};
    float mrun[4] = {-1e30f, -1e30f, -1e30f, -1e30f};
    float lrun[4] = {0.f, 0.f, 0.f, 0.f};

    const int srow = tid >> 3, c8 = (tid & 7) << 3;
    char* vbase = (char*)Vts;

    for (int s0 = 0; s0 < T; s0 += 64) {
        __syncthreads();
        #pragma unroll
        for (int it = 0; it < 2; it++) {
            int r = srow + it * 32;
            size_t g = base + (size_t)(s0 + r) * 64 + c8;
            *(uint4*)&Ksh[r][c8] = *(const uint4*)&Kh[g];
            *(uint4*)&Ksl[r][c8] = *(const uint4*)&Kl[g];
            // V^T tile: rows = v, cols = s; global Vt[(bh*64+v)*2048 + s0 + c8]
            uint4 vv = *(const uint4*)&Vt[((size_t)(bh * 64 + r) << 11) + s0 + c8];
            int byteoff = r * 128 + ((c8 * 2) ^ ((r & 7) << 4));
            *(uint4*)(vbase + byteoff) = vv;
        }
        __syncthreads();

        // scores: S = Q (16x64) . K^T (64x64), split hi/lo -> four 16x16 fragments
        f32x4 sc[4];
        #pragma unroll
        for (int c = 0; c < 4; c++) {
            bf16x8 b0h = *(const bf16x8*)&Ksh[c * 16 + fr][fg * 8];
            bf16x8 b1h = *(const bf16x8*)&Ksh[c * 16 + fr][32 + fg * 8];
            bf16x8 b0l = *(const bf16x8*)&Ksl[c * 16 + fr][fg * 8];
            bf16x8 b1l = *(const bf16x8*)&Ksl[c * 16 + fr][32 + fg * 8];
            f32x4 z = f32x4{0.f, 0.f, 0.f, 0.f};
            z = MFMA_BF16(aq0h, b0h, z);
            z = MFMA_BF16(aq0l, b0h, z);
            z = MFMA_BF16(aq0h, b0l, z);
            z = MFMA_BF16(aq1h, b1h, z);
            z = MFMA_BF16(aq1l, b1h, z);
            z = MFMA_BF16(aq1h, b1l, z);
            sc[c] = z * 0.125f;   // 1/sqrt(64)
        }

        // online softmax (rows live across the 16-lane group; 4 rows/lane)
        float alpha[4];
        #pragma unroll
        for (int r = 0; r < 4; r++) {
            float v = fmaxf(fmaxf(sc[0][r], sc[1][r]), fmaxf(sc[2][r], sc[3][r]));
            v = fmaxf(v, __shfl_xor(v, 1)); v = fmaxf(v, __shfl_xor(v, 2));
            v = fmaxf(v, __shfl_xor(v, 4)); v = fmaxf(v, __shfl_xor(v, 8));
            float mn = fmaxf(mrun[r], v);
            alpha[r] = __expf(mrun[r] - mn);
            mrun[r] = mn;
        }
        float rs[4] = {0.f, 0.f, 0.f, 0.f};
        #pragma unroll
        for (int c = 0; c < 4; c++)
            #pragma unroll
            for (int r = 0; r < 4; r++) {
                float p = __expf(sc[c][r] - mrun[r]);
                sc[c][r] = p;
                rs[r] += p;
            }
        #pragma unroll
        for (int r = 0; r < 4; r++) {
            float t = rs[r];
            t += __shfl_xor(t, 1); t += __shfl_xor(t, 2);
            t += __shfl_xor(t, 4); t += __shfl_xor(t, 8);
            lrun[r] = lrun[r] * alpha[r] + t;
            #pragma unroll
            for (int n = 0; n < 4; n++) o[n][r] *= alpha[r];
        }

        // P (D-layout) -> LDS -> A-layout for PV
        #pragma unroll
        for (int c = 0; c < 4; c++)
            #pragma unroll
            for (int r = 0; r < 4; r++)
                Plds[wave][fg * 4 + r][c * 16 + fr] = f2bf(sc[c][r]);
        __syncthreads();

        bf16x8 pa0 = *(const bf16x8*)&Plds[wave][fr][fg * 8];
        bf16x8 pa1 = *(const bf16x8*)&Plds[wave][fr][32 + fg * 8];
        #pragma unroll
        for (int n = 0; n < 4; n++) {
            int row = n * 16 + fr;
            bf16x8 bv0 = *(const bf16x8*)(vbase + row * 128 + ((fg * 16)      ^ ((row & 7) << 4)));
            bf16x8 bv1 = *(const bf16x8*)(vbase + row * 128 + ((64 + fg * 16) ^ ((row & 7) << 4)));
            o[n] = MFMA_BF16(pa0, bv0, o[n]);
            o[n] = MFMA_BF16(pa1, bv1, o[n]);
        }
    }

    #pragma unroll
    for (int r = 0; r < 4; r++) {
        float inv = 1.0f / lrun[r];
        #pragma unroll
        for (int n = 0; n < 4; n++) o[n][r] *= inv;
    }
    #pragma unroll
    for (int n = 0; n < 4; n++)
        #pragma unroll
        for (int r = 0; r < 4; r++)
            Ob[base + (size_t)(q0 + wave * 16 + fg * 4 + r) * 64 + n * 16 + fr] = f2bf(o[n][r]);
}

// ---------------- launch ----------------
extern "C" void kernel_launch(void* const* d_in, const int* in_sizes, int n_in,
                              void* d_out, int out_size, void* d_ws, size_t ws_size,
                              hipStream_t stream)
{
    const float* x  = (const float*)d_in[0];
    const float* Wq = (const float*)d_in[1];
    const float* Wk = (const float*)d_in[2];
    const float* Wv = (const float*)d_in[3];
    const float* Wo = (const float*)d_in[4];
    const float* W1 = (const float*)d_in[5];
    const float* b1 = (const float*)d_in[6];
    const float* W2 = (const float*)d_in[7];
    const float* b2 = (const float*)d_in[8];
    float* out = (float*)d_out;

    char* ws = (char*)d_ws;
    size_t off = 0;
    auto alloc = [&](size_t bytes) -> void* {
        void* p = ws + off; off += (bytes + 255) & ~(size_t)255; return p;
    };
    unsigned short* wqkTh = (unsigned short*)alloc(1024ull * 512 * 2);
    unsigned short* wqkTl = (unsigned short*)alloc(1024ull * 512 * 2);
    unsigned short* wvT   = (unsigned short*)alloc(512ull * 512 * 2);
    unsigned short* woT   = (unsigned short*)alloc(512ull * 512 * 2);
    unsigned short* w1T   = (unsigned short*)alloc(2048ull * 512 * 2);
    unsigned short* w2T   = (unsigned short*)alloc(512ull * 2048 * 2);
    unsigned short* Qhb   = (unsigned short*)alloc(8192ull * 512 * 2);  // Qh,Ql,Kh,Kl are
    unsigned short* Qlb   = (unsigned short*)alloc(8192ull * 512 * 2);  // contiguous 32MB,
    unsigned short* Khb   = (unsigned short*)alloc(8192ull * 512 * 2);  // reused as hb later
    unsigned short* Klb   = (unsigned short*)alloc(8192ull * 512 * 2);
    unsigned short* Vtb   = (unsigned short*)alloc(8192ull * 512 * 2);  // (b,h,k,t)
    unsigned short* xh    = (unsigned short*)alloc(8192ull * 512 * 2);
    unsigned short* xl    = (unsigned short*)alloc(8192ull * 512 * 2);
    // aliases (lifetimes do not overlap):
    unsigned short* attb = xh;   // attn out, after QK/Vt GEMMs consumed xh/xl
    unsigned short* outb = xl;   // Wo out
    unsigned short* hb   = Qhb;  // FF1 out (32MB across Qh..Kl), after attention

    k_cvt_split<<<8192 * 512 / 4 / 256, 256, 0, stream>>>(
        (const float4*)x, (ushort4*)xh, (ushort4*)xl, 8192 * 512 / 4);
    // W_qk: per-head transpose (512x64 -> 64x512), fused rows t*512+h*64+k
    k_transT<<<dim3(2, 16, 8), 256, 0, stream>>>(Wq, 512 * 64, wqkTh, wqkTl, 512, 64, 0);
    k_transT<<<dim3(2, 16, 8), 256, 0, stream>>>(Wk, 512 * 64, wqkTh, wqkTl, 512, 64, 512 * 512);
    k_transT<<<dim3(2, 16, 8), 256, 0, stream>>>(Wv, 512 * 64, wvT, nullptr, 512, 64, 0);
    k_transT<<<dim3(16, 16, 1), 256, 0, stream>>>(Wo, 0, woT, nullptr, 512, 512, 0);
    k_transT<<<dim3(64, 16, 1), 256, 0, stream>>>(W1, 0, w1T, nullptr, 512, 2048, 0);
    k_transT<<<dim3(16, 64, 1), 256, 0, stream>>>(W2, 0, w2T, nullptr, 2048, 512, 0);

    // QK projection (split precision): (8192x512) @ (512x1024) -> Q/K hi+lo
    gemm_bt<3, true><<<dim3(1024 / 128, 8192 / 128), 256, 0, stream>>>(
        xh, xl, wqkTh, wqkTl, 8192, 1024, 512, nullptr,
        nullptr, nullptr, Qhb, Qlb, Khb, Klb, nullptr);

    // V^T projection: rows = (h,k) 512, cols = (b,t) 8192 -> Vt[(b,h),k,t]
    gemm_bt<4, false><<<dim3(8192 / 128, 512 / 128), 256, 0, stream>>>(
        wvT, nullptr, xh, nullptr, 512, 8192, 512, nullptr,
        nullptr, nullptr, nullptr, nullptr, nullptr, nullptr, Vtb);

    // attention -> attb (B,H,T,64) flat == (B,T',512) for the Wo GEMM (raw reshape)
    attn_kernel<<<4 * 8 * (2048 / 64), 256, 0, stream>>>(Qhb, Qlb, Khb, Klb, Vtb, attb);

    // out = att' @ Wo
    gemm_bt<0, false><<<dim3(512 / 128, 8192 / 128), 256, 0, stream>>>(
        attb, nullptr, woT, nullptr, 8192, 512, 512, nullptr,
        outb, nullptr, nullptr, nullptr, nullptr, nullptr, nullptr);

    // h = relu(out @ W1 + b1)
    gemm_bt<1, false><<<dim3(2048 / 128, 8192 / 128), 256, 0, stream>>>(
        outb, nullptr, w1T, nullptr, 8192, 2048, 512, b1,
        hb, nullptr, nullptr, nullptr, nullptr, nullptr, nullptr);

    // y = h @ W2 + b2  (f32 output)
    gemm_bt<2, false><<<dim3(512 / 128, 8192 / 128), 256, 0, stream>>>(
        hb, nullptr, w2T, nullptr, 8192, 512, 2048, b2,
        nullptr, out, nullptr, nullptr, nullptr, nullptr, nullptr);
}

// Round 7
// 380.687 us; speedup vs baseline: 1.2994x; 1.0212x over previous
//
#include <hip/hip_runtime.h>
#include <hip/hip_bf16.h>

typedef short bf16x8 __attribute__((ext_vector_type(8)));
typedef float f32x4 __attribute__((ext_vector_type(4)));

#define MFMA_BF16(A,B,C) __builtin_amdgcn_mfma_f32_16x16x32_bf16((A),(B),(C),0,0,0)

__device__ __forceinline__ unsigned short f2bf(float f){
    union { float f; unsigned u; } v; v.f = f;
    unsigned r = v.u + 0x7fffu + ((v.u >> 16) & 1u);
    return (unsigned short)(r >> 16);
}
__device__ __forceinline__ float bf2f(unsigned short h){
    union { unsigned u; float f; } v; v.u = ((unsigned)h) << 16; return v.f;
}

// async global->LDS, 16B per lane; lds dest = wave-uniform base + lane*16
__device__ __forceinline__ void gl_lds16(const unsigned short* g, void* l){
    __builtin_amdgcn_global_load_lds(
        (const __attribute__((address_space(1))) unsigned int*)g,
        (__attribute__((address_space(3))) unsigned int*)l, 16, 0, 0);
}

// ---------------- prep kernels ----------------
__global__ __launch_bounds__(256) void k_cvt_split(const float4* __restrict__ in,
                                                   ushort4* __restrict__ hi,
                                                   ushort4* __restrict__ lo, int n4){
    int i = blockIdx.x * 256 + threadIdx.x;
    if (i < n4) {
        float4 v = in[i];
        ushort4 h, l;
        h.x = f2bf(v.x); l.x = f2bf(v.x - bf2f(h.x));
        h.y = f2bf(v.y); l.y = f2bf(v.y - bf2f(h.y));
        h.z = f2bf(v.z); l.z = f2bf(v.z - bf2f(h.z));
        h.w = f2bf(v.w); l.w = f2bf(v.w - bf2f(h.w));
        hi[i] = h; lo[i] = l;
    }
}

// tiled transpose+cast (+optional split): in f32 (R x C) per head -> out bf16 (C x R)
__global__ __launch_bounds__(256)
void k_transT(const float* __restrict__ in, long inHeadStride,
              unsigned short* __restrict__ hi, unsigned short* __restrict__ lo,
              int R, int C, long outBase){
    __shared__ float t[32][33];
    const float* src = in + (size_t)blockIdx.z * inHeadStride;
    int c0 = blockIdx.x * 32, r0 = blockIdx.y * 32;
    int tx = threadIdx.x & 31, ty = threadIdx.x >> 5;   // 32 x 8
    #pragma unroll
    for (int i = 0; i < 4; i++)
        t[ty + i * 8][tx] = src[(size_t)(r0 + ty + i * 8) * C + c0 + tx];
    __syncthreads();
    size_t ob = (size_t)outBase + (size_t)blockIdx.z * C * R;
    #pragma unroll
    for (int i = 0; i < 4; i++) {
        int c = c0 + ty + i * 8, r = r0 + tx;
        float v = t[tx][ty + i * 8];
        unsigned short hh = f2bf(v);
        hi[ob + (size_t)c * R + r] = hh;
        if (lo) lo[ob + (size_t)c * R + r] = f2bf(v - bf2f(hh));
    }
}

// ---------------- GEMM 128x128: C = A(MxK) * Bt(NxK)^T ----------------
// EPI: 1 = bias+relu bf16 out, 3 = QK split scatter
template<int EPI, bool SPLIT>
__global__ __launch_bounds__(256)
void gemm_bt(const unsigned short* __restrict__ Ah, const unsigned short* __restrict__ Al,
             const unsigned short* __restrict__ Bh, const unsigned short* __restrict__ Bl,
             int M, int N, int K, const float* __restrict__ bias,
             unsigned short* __restrict__ Cb, float* __restrict__ Cf,
             unsigned short* __restrict__ Qh, unsigned short* __restrict__ Ql,
             unsigned short* __restrict__ Kh, unsigned short* __restrict__ Kl,
             unsigned short* __restrict__ Vo)
{
    constexpr int BK = 32;
    constexpr int NS = SPLIT ? 2 : 1;
    __shared__ __align__(16) unsigned short As[NS][128][BK];
    __shared__ __align__(16) unsigned short Bs[NS][128][BK];

    const int tid = threadIdx.x, lane = tid & 63, wave = tid >> 6;
    const int wr = wave >> 1, wc = wave & 1;
    const int rA0 = blockIdx.y * 128, cB0 = blockIdx.x * 128;
    const int fr = lane & 15, fg = lane >> 4;

    f32x4 acc[4][4];
    #pragma unroll
    for (int m = 0; m < 4; m++)
        #pragma unroll
        for (int n = 0; n < 4; n++)
            acc[m][n] = f32x4{0.f, 0.f, 0.f, 0.f};

    for (int kt = 0; kt < K; kt += BK) {
        __syncthreads();
        #pragma unroll
        for (int q = 0; q < 2; q++) {
            int ch = q * 256 + tid;
            int r = ch >> 2, kk = (ch & 3) << 3;
            size_t ga = (size_t)(rA0 + r) * K + kt + kk;
            size_t gb = (size_t)(cB0 + r) * K + kt + kk;
            char* la0 = (char*)&As[0][0][0] + (q * 256 + wave * 64) * 16;
            char* lb0 = (char*)&Bs[0][0][0] + (q * 256 + wave * 64) * 16;
            gl_lds16(&Ah[ga], la0);
            gl_lds16(&Bh[gb], lb0);
            if constexpr (SPLIT) {
                char* la1 = (char*)&As[1][0][0] + (q * 256 + wave * 64) * 16;
                char* lb1 = (char*)&Bs[1][0][0] + (q * 256 + wave * 64) * 16;
                gl_lds16(&Al[ga], la1);
                gl_lds16(&Bl[gb], lb1);
            }
        }
        __syncthreads();

        bf16x8 afh[4], bfh[4], afl[4], bfl[4];
        #pragma unroll
        for (int m = 0; m < 4; m++) afh[m] = *(const bf16x8*)&As[0][wr * 64 + m * 16 + fr][fg * 8];
        #pragma unroll
        for (int n = 0; n < 4; n++) bfh[n] = *(const bf16x8*)&Bs[0][wc * 64 + n * 16 + fr][fg * 8];
        if constexpr (SPLIT) {
            #pragma unroll
            for (int m = 0; m < 4; m++) afl[m] = *(const bf16x8*)&As[1][wr * 64 + m * 16 + fr][fg * 8];
            #pragma unroll
            for (int n = 0; n < 4; n++) bfl[n] = *(const bf16x8*)&Bs[1][wc * 64 + n * 16 + fr][fg * 8];
        }
        #pragma unroll
        for (int m = 0; m < 4; m++)
            #pragma unroll
            for (int n = 0; n < 4; n++) {
                acc[m][n] = MFMA_BF16(afh[m], bfh[n], acc[m][n]);
                if constexpr (SPLIT) {
                    acc[m][n] = MFMA_BF16(afl[m], bfh[n], acc[m][n]);
                    acc[m][n] = MFMA_BF16(afh[m], bfl[n], acc[m][n]);
                }
            }
    }

    #pragma unroll
    for (int m = 0; m < 4; m++) {
        #pragma unroll
        for (int n = 0; n < 4; n++) {
            #pragma unroll
            for (int j = 0; j < 4; j++) {
                int row = rA0 + wr * 64 + m * 16 + fg * 4 + j;
                int col = cB0 + wc * 64 + n * 16 + fr;
                float v = acc[m][n][j];
                if constexpr (EPI == 1) {
                    v += bias[col];
                    v = fmaxf(v, 0.f);
                    Cb[(size_t)row * N + col] = f2bf(v);
                } else {  // EPI == 3: col = t*512 + h*64 + k (t:0=Q,1=K); row = b*2048+tt
                    int t = col >> 9, h = (col >> 6) & 7, k = col & 63;
                    int b = row >> 11, tt = row & 2047;
                    size_t di = ((size_t)((b << 3) + h) * 2048 + tt) * 64 + k;
                    unsigned short hh = f2bf(v);
                    if (t == 0) { Qh[di] = hh; Ql[di] = f2bf(v - bf2f(hh)); }
                    else        { Kh[di] = hh; Kl[di] = f2bf(v - bf2f(hh)); }
                }
            }
        }
    }
}

// ---------------- GEMM 64x64 (4 waves, 32x32/wave) for skinny shapes -------
// EPI: 0 = bf16 out, 2 = bias f32 out, 4 = Vt scatter
template<int EPI>
__global__ __launch_bounds__(256)
void gemm64(const unsigned short* __restrict__ A, const unsigned short* __restrict__ Bt,
            int M, int N, int K, const float* __restrict__ bias,
            unsigned short* __restrict__ Cb, float* __restrict__ Cf,
            unsigned short* __restrict__ Vo)
{
    constexpr int BK = 32;
    __shared__ __align__(16) unsigned short As[64][BK];
    __shared__ __align__(16) unsigned short Bs[64][BK];

    const int tid = threadIdx.x, lane = tid & 63, wave = tid >> 6;
    const int wr = wave >> 1, wc = wave & 1;
    const int rA0 = blockIdx.y * 64, cB0 = blockIdx.x * 64;
    const int fr = lane & 15, fg = lane >> 4;

    f32x4 acc[2][2];
    #pragma unroll
    for (int m = 0; m < 2; m++)
        #pragma unroll
        for (int n = 0; n < 2; n++)
            acc[m][n] = f32x4{0.f, 0.f, 0.f, 0.f};

    // 256 chunks of 16B per tile -> exactly 1 chunk/thread per tile
    const int r = tid >> 2, kk = (tid & 3) << 3;
    for (int kt = 0; kt < K; kt += BK) {
        __syncthreads();
        gl_lds16(&A [(size_t)(rA0 + r) * K + kt + kk], (char*)&As[0][0] + wave * 1024);
        gl_lds16(&Bt[(size_t)(cB0 + r) * K + kt + kk], (char*)&Bs[0][0] + wave * 1024);
        __syncthreads();

        bf16x8 af[2], bf[2];
        #pragma unroll
        for (int m = 0; m < 2; m++) af[m] = *(const bf16x8*)&As[wr * 32 + m * 16 + fr][fg * 8];
        #pragma unroll
        for (int n = 0; n < 2; n++) bf[n] = *(const bf16x8*)&Bs[wc * 32 + n * 16 + fr][fg * 8];
        #pragma unroll
        for (int m = 0; m < 2; m++)
            #pragma unroll
            for (int n = 0; n < 2; n++)
                acc[m][n] = MFMA_BF16(af[m], bf[n], acc[m][n]);
    }

    #pragma unroll
    for (int m = 0; m < 2; m++) {
        #pragma unroll
        for (int n = 0; n < 2; n++) {
            #pragma unroll
            for (int j = 0; j < 4; j++) {
                int row = rA0 + wr * 32 + m * 16 + fg * 4 + j;
                int col = cB0 + wc * 32 + n * 16 + fr;
                float v = acc[m][n][j];
                if constexpr (EPI == 2) v += bias[col];
                if constexpr (EPI == 0) {
                    Cb[(size_t)row * N + col] = f2bf(v);
                } else if constexpr (EPI == 2) {
                    Cf[(size_t)row * N + col] = v;
                } else {  // EPI==4: row = h*64+k, col = b*2048+t -> Vt[((b*8+h)*64+k)*2048+t]
                    int h = row >> 6, k = row & 63;
                    int b = col >> 11, tt = col & 2047;
                    Vo[(((size_t)(b * 8 + h) * 64 + k) << 11) + tt] = f2bf(v);
                }
            }
        }
    }
}

// ---------------- flash attention (split-precision QK^T, pre-transposed V) --
// grid.x = B*H*(T/64); 4 waves, each owns 16 q-rows; 64 keys per iteration
__global__ __launch_bounds__(256)
void attn_kernel(const unsigned short* __restrict__ Qh, const unsigned short* __restrict__ Ql,
                 const unsigned short* __restrict__ Kh, const unsigned short* __restrict__ Kl,
                 const unsigned short* __restrict__ Vt, unsigned short* __restrict__ Ob)
{
    constexpr int T = 2048;
    __shared__ __align__(16) unsigned short Ksh[64][72];     // K hi rows (s-major), padded
    __shared__ __align__(16) unsigned short Ksl[64][72];     // K lo rows
    __shared__ __align__(16) unsigned short Vts[64 * 64];    // [v][s], XOR-swizzled 16B slots
    __shared__ __align__(16) unsigned short Plds[4][16][72]; // per-wave P, [q][s]

    const int tid = threadIdx.x, lane = tid & 63, wave = tid >> 6;
    const int bh = blockIdx.x >> 5;
    const int q0 = (blockIdx.x & 31) * 64;
    const size_t base = (size_t)bh * T * 64;
    const int fr = lane & 15, fg = lane >> 4;

    const size_t qoff = base + (size_t)(q0 + wave * 16 + fr) * 64;
    bf16x8 aq0h = *(const bf16x8*)&Qh[qoff + fg * 8];
    bf16x8 aq1h = *(const bf16x8*)&Qh[qoff + 32 + fg * 8];
    bf16x8 aq0l = *(const bf16x8*)&Ql[qoff + fg * 8];
    bf16x8 aq1l = *(const bf16x8*)&Ql[qoff + 32 + fg * 8];

    f32x4 o[4];
    #pragma unroll
    for (int n = 0; n < 4; n++) o[n] = f32x4{0.f, 0.f, 0.f, 0.f};
    float mrun[4] = {-1e30f, -1e30f, -1e30f, -1e30f};
    float lrun[4] = {0.f, 0.f, 0.f, 0.f};

    const int srow = tid >> 3, c8 = (tid & 7) << 3;
    char* vbase = (char*)Vts;

    for (int s0 = 0; s0 < T; s0 += 64) {
        __syncthreads();
        #pragma unroll
        for (int it = 0; it < 2; it++) {
            int r = srow + it * 32;
            size_t g = base + (size_t)(s0 + r) * 64 + c8;
            *(uint4*)&Ksh[r][c8] = *(const uint4*)&Kh[g];
            *(uint4*)&Ksl[r][c8] = *(const uint4*)&Kl[g];
            // V^T tile: rows = v, cols = s; global Vt[(bh*64+v)*2048 + s0 + c8]
            uint4 vv = *(const uint4*)&Vt[((size_t)(bh * 64 + r) << 11) + s0 + c8];
            int byteoff = r * 128 + ((c8 * 2) ^ ((r & 7) << 4));
            *(uint4*)(vbase + byteoff) = vv;
        }
        __syncthreads();

        // scores: S = Q (16x64) . K^T (64x64), split hi/lo -> four 16x16 fragments
        f32x4 sc[4];
        #pragma unroll
        for (int c = 0; c < 4; c++) {
            bf16x8 b0h = *(const bf16x8*)&Ksh[c * 16 + fr][fg * 8];
            bf16x8 b1h = *(const bf16x8*)&Ksh[c * 16 + fr][32 + fg * 8];
            bf16x8 b0l = *(const bf16x8*)&Ksl[c * 16 + fr][fg * 8];
            bf16x8 b1l = *(const bf16x8*)&Ksl[c * 16 + fr][32 + fg * 8];
            f32x4 z = f32x4{0.f, 0.f, 0.f, 0.f};
            z = MFMA_BF16(aq0h, b0h, z);
            z = MFMA_BF16(aq0l, b0h, z);
            z = MFMA_BF16(aq0h, b0l, z);
            z = MFMA_BF16(aq1h, b1h, z);
            z = MFMA_BF16(aq1l, b1h, z);
            z = MFMA_BF16(aq1h, b1l, z);
            sc[c] = z * 0.125f;   // 1/sqrt(64)
        }

        // online softmax (rows live across the 16-lane group; 4 rows/lane)
        float alpha[4];
        #pragma unroll
        for (int r2 = 0; r2 < 4; r2++) {
            float v = fmaxf(fmaxf(sc[0][r2], sc[1][r2]), fmaxf(sc[2][r2], sc[3][r2]));
            v = fmaxf(v, __shfl_xor(v, 1)); v = fmaxf(v, __shfl_xor(v, 2));
            v = fmaxf(v, __shfl_xor(v, 4)); v = fmaxf(v, __shfl_xor(v, 8));
            float mn = fmaxf(mrun[r2], v);
            alpha[r2] = __expf(mrun[r2] - mn);
            mrun[r2] = mn;
        }
        float rs[4] = {0.f, 0.f, 0.f, 0.f};
        #pragma unroll
        for (int c = 0; c < 4; c++)
            #pragma unroll
            for (int r2 = 0; r2 < 4; r2++) {
                float p = __expf(sc[c][r2] - mrun[r2]);
                sc[c][r2] = p;
                rs[r2] += p;
            }
        #pragma unroll
        for (int r2 = 0; r2 < 4; r2++) {
            float t = rs[r2];
            t += __shfl_xor(t, 1); t += __shfl_xor(t, 2);
            t += __shfl_xor(t, 4); t += __shfl_xor(t, 8);
            lrun[r2] = lrun[r2] * alpha[r2] + t;
            #pragma unroll
            for (int n = 0; n < 4; n++) o[n][r2] *= alpha[r2];
        }

        // P (D-layout) -> LDS -> A-layout for PV
        #pragma unroll
        for (int c = 0; c < 4; c++)
            #pragma unroll
            for (int r2 = 0; r2 < 4; r2++)
                Plds[wave][fg * 4 + r2][c * 16 + fr] = f2bf(sc[c][r2]);
        __syncthreads();

        bf16x8 pa0 = *(const bf16x8*)&Plds[wave][fr][fg * 8];
        bf16x8 pa1 = *(const bf16x8*)&Plds[wave][fr][32 + fg * 8];
        #pragma unroll
        for (int n = 0; n < 4; n++) {
            int row = n * 16 + fr;
            bf16x8 bv0 = *(const bf16x8*)(vbase + row * 128 + ((fg * 16)      ^ ((row & 7) << 4)));
            bf16x8 bv1 = *(const bf16x8*)(vbase + row * 128 + ((64 + fg * 16) ^ ((row & 7) << 4)));
            o[n] = MFMA_BF16(pa0, bv0, o[n]);
            o[n] = MFMA_BF16(pa1, bv1, o[n]);
        }
    }

    #pragma unroll
    for (int r2 = 0; r2 < 4; r2++) {
        float inv = 1.0f / lrun[r2];
        #pragma unroll
        for (int n = 0; n < 4; n++) o[n][r2] *= inv;
    }
    #pragma unroll
    for (int n = 0; n < 4; n++)
        #pragma unroll
        for (int r2 = 0; r2 < 4; r2++)
            Ob[base + (size_t)(q0 + wave * 16 + fg * 4 + r2) * 64 + n * 16 + fr] = f2bf(o[n][r2]);
}

// ---------------- launch ----------------
extern "C" void kernel_launch(void* const* d_in, const int* in_sizes, int n_in,
                              void* d_out, int out_size, void* d_ws, size_t ws_size,
                              hipStream_t stream)
{
    const float* x  = (const float*)d_in[0];
    const float* Wq = (const float*)d_in[1];
    const float* Wk = (const float*)d_in[2];
    const float* Wv = (const float*)d_in[3];
    const float* Wo = (const float*)d_in[4];
    const float* W1 = (const float*)d_in[5];
    const float* b1 = (const float*)d_in[6];
    const float* W2 = (const float*)d_in[7];
    const float* b2 = (const float*)d_in[8];
    float* out = (float*)d_out;

    char* ws = (char*)d_ws;
    size_t off = 0;
    auto alloc = [&](size_t bytes) -> void* {
        void* p = ws + off; off += (bytes + 255) & ~(size_t)255; return p;
    };
    unsigned short* wqkTh = (unsigned short*)alloc(1024ull * 512 * 2);
    unsigned short* wqkTl = (unsigned short*)alloc(1024ull * 512 * 2);
    unsigned short* wvT   = (unsigned short*)alloc(512ull * 512 * 2);
    unsigned short* woT   = (unsigned short*)alloc(512ull * 512 * 2);
    unsigned short* w1T   = (unsigned short*)alloc(2048ull * 512 * 2);
    unsigned short* w2T   = (unsigned short*)alloc(512ull * 2048 * 2);
    unsigned short* Qhb   = (unsigned short*)alloc(8192ull * 512 * 2);
    unsigned short* Qlb   = (unsigned short*)alloc(8192ull * 512 * 2);
    unsigned short* Khb   = (unsigned short*)alloc(8192ull * 512 * 2);
    unsigned short* Klb   = (unsigned short*)alloc(8192ull * 512 * 2);
    unsigned short* Vtb   = (unsigned short*)alloc(8192ull * 512 * 2);
    unsigned short* xh    = (unsigned short*)alloc(8192ull * 512 * 2);
    unsigned short* xl    = (unsigned short*)alloc(8192ull * 512 * 2);
    // aliases (lifetimes do not overlap):
    unsigned short* attb = xh;   // attn out, after QK/Vt GEMMs consumed xh/xl
    unsigned short* outb = xl;   // Wo out
    unsigned short* hb   = Qhb;  // FF1 out (32MB across Qh..Kl), after attention

    k_cvt_split<<<8192 * 512 / 4 / 256, 256, 0, stream>>>(
        (const float4*)x, (ushort4*)xh, (ushort4*)xl, 8192 * 512 / 4);
    k_transT<<<dim3(2, 16, 8), 256, 0, stream>>>(Wq, 512 * 64, wqkTh, wqkTl, 512, 64, 0);
    k_transT<<<dim3(2, 16, 8), 256, 0, stream>>>(Wk, 512 * 64, wqkTh, wqkTl, 512, 64, 512 * 512);
    k_transT<<<dim3(2, 16, 8), 256, 0, stream>>>(Wv, 512 * 64, wvT, nullptr, 512, 64, 0);
    k_transT<<<dim3(16, 16, 1), 256, 0, stream>>>(Wo, 0, woT, nullptr, 512, 512, 0);
    k_transT<<<dim3(64, 16, 1), 256, 0, stream>>>(W1, 0, w1T, nullptr, 512, 2048, 0);
    k_transT<<<dim3(16, 64, 1), 256, 0, stream>>>(W2, 0, w2T, nullptr, 2048, 512, 0);

    // QK projection (split precision): (8192x512) @ (512x1024) -> Q/K hi+lo
    gemm_bt<3, true><<<dim3(1024 / 128, 8192 / 128), 256, 0, stream>>>(
        xh, xl, wqkTh, wqkTl, 8192, 1024, 512, nullptr,
        nullptr, nullptr, Qhb, Qlb, Khb, Klb, nullptr);

    // V^T projection (64x64 tiles): rows = (h,k) 512, cols = (b,t) 8192 -> Vt
    gemm64<4><<<dim3(8192 / 64, 512 / 64), 256, 0, stream>>>(
        wvT, xh, 512, 8192, 512, nullptr, nullptr, nullptr, Vtb);

    // attention -> attb (B,H,T,64) flat == (B,T',512) for the Wo GEMM (raw reshape)
    attn_kernel<<<4 * 8 * (2048 / 64), 256, 0, stream>>>(Qhb, Qlb, Khb, Klb, Vtb, attb);

    // out = att' @ Wo   (64x64 tiles: grid 1024 -> 4 blocks/CU)
    gemm64<0><<<dim3(512 / 64, 8192 / 64), 256, 0, stream>>>(
        attb, woT, 8192, 512, 512, nullptr, outb, nullptr, nullptr);

    // h = relu(out @ W1 + b1)   (128x128 tiles: grid 1024)
    gemm_bt<1, false><<<dim3(2048 / 128, 8192 / 128), 256, 0, stream>>>(
        outb, nullptr, w1T, nullptr, 8192, 2048, 512, b1,
        hb, nullptr, nullptr, nullptr, nullptr, nullptr, nullptr);

    // y = h @ W2 + b2  (f32 output; 64x64 tiles: grid 1024)
    gemm64<2><<<dim3(512 / 64, 8192 / 64), 256, 0, stream>>>(
        hb, w2T, 8192, 512, 2048, b2, nullptr, out, nullptr);
}

// Round 10
// 362.679 us; speedup vs baseline: 1.3639x; 1.0497x over previous
//
#include <hip/hip_runtime.h>
#include <hip/hip_bf16.h>

typedef short bf16x8 __attribute__((ext_vector_type(8)));
typedef float f32x4 __attribute__((ext_vector_type(4)));

#define MFMA_BF16(A,B,C) __builtin_amdgcn_mfma_f32_16x16x32_bf16((A),(B),(C),0,0,0)

__device__ __forceinline__ unsigned short f2bf(float f){
    union { float f; unsigned u; } v; v.f = f;
    unsigned r = v.u + 0x7fffu + ((v.u >> 16) & 1u);
    return (unsigned short)(r >> 16);
}
__device__ __forceinline__ float bf2f(unsigned short h){
    union { unsigned u; float f; } v; v.u = ((unsigned)h) << 16; return v.f;
}

// async global->LDS, 16B per lane; lds dest = wave-uniform base (+lane*16 implicit)
__device__ __forceinline__ void gl_lds16(const unsigned short* g, void* l){
    __builtin_amdgcn_global_load_lds(
        (const __attribute__((address_space(1))) unsigned int*)g,
        (__attribute__((address_space(3))) unsigned int*)l, 16, 0, 0);
}

// ---------------- prep kernels ----------------
__global__ __launch_bounds__(256) void k_cvt_split(const float4* __restrict__ in,
                                                   ushort4* __restrict__ hi,
                                                   ushort4* __restrict__ lo, int n4){
    int i = blockIdx.x * 256 + threadIdx.x;
    if (i < n4) {
        float4 v = in[i];
        ushort4 h, l;
        h.x = f2bf(v.x); l.x = f2bf(v.x - bf2f(h.x));
        h.y = f2bf(v.y); l.y = f2bf(v.y - bf2f(h.y));
        h.z = f2bf(v.z); l.z = f2bf(v.z - bf2f(h.z));
        h.w = f2bf(v.w); l.w = f2bf(v.w - bf2f(h.w));
        hi[i] = h; lo[i] = l;
    }
}

// tiled transpose+cast (+optional split): in f32 (R x C) per head -> out bf16 (C x R)
__global__ __launch_bounds__(256)
void k_transT(const float* __restrict__ in, long inHeadStride,
              unsigned short* __restrict__ hi, unsigned short* __restrict__ lo,
              int R, int C, long outBase){
    __shared__ float t[32][33];
    const float* src = in + (size_t)blockIdx.z * inHeadStride;
    int c0 = blockIdx.x * 32, r0 = blockIdx.y * 32;
    int tx = threadIdx.x & 31, ty = threadIdx.x >> 5;   // 32 x 8
    #pragma unroll
    for (int i = 0; i < 4; i++)
        t[ty + i * 8][tx] = src[(size_t)(r0 + ty + i * 8) * C + c0 + tx];
    __syncthreads();
    size_t ob = (size_t)outBase + (size_t)blockIdx.z * C * R;
    #pragma unroll
    for (int i = 0; i < 4; i++) {
        int c = c0 + ty + i * 8, r = r0 + tx;
        float v = t[tx][ty + i * 8];
        unsigned short hh = f2bf(v);
        hi[ob + (size_t)c * R + r] = hh;
        if (lo) lo[ob + (size_t)c * R + r] = f2bf(v - bf2f(hh));
    }
}

// ---------------- GEMM 128x128: C = A(MxK) * Bt(NxK)^T ----------------
// EPI: 1 = bias+relu bf16 out, 3 = QK split scatter
template<int EPI, bool SPLIT>
__global__ __launch_bounds__(256)
void gemm_bt(const unsigned short* __restrict__ Ah, const unsigned short* __restrict__ Al,
             const unsigned short* __restrict__ Bh, const unsigned short* __restrict__ Bl,
             int M, int N, int K, const float* __restrict__ bias,
             unsigned short* __restrict__ Cb, float* __restrict__ Cf,
             unsigned short* __restrict__ Qh, unsigned short* __restrict__ Ql,
             unsigned short* __restrict__ Kh, unsigned short* __restrict__ Kl,
             unsigned short* __restrict__ Vo)
{
    constexpr int BK = 32;
    constexpr int NS = SPLIT ? 2 : 1;
    __shared__ __align__(16) unsigned short As[NS][128][BK];
    __shared__ __align__(16) unsigned short Bs[NS][128][BK];

    const int tid = threadIdx.x, lane = tid & 63, wave = tid >> 6;
    const int wr = wave >> 1, wc = wave & 1;
    const int rA0 = blockIdx.y * 128, cB0 = blockIdx.x * 128;
    const int fr = lane & 15, fg = lane >> 4;

    f32x4 acc[4][4];
    #pragma unroll
    for (int m = 0; m < 4; m++)
        #pragma unroll
        for (int n = 0; n < 4; n++)
            acc[m][n] = f32x4{0.f, 0.f, 0.f, 0.f};

    for (int kt = 0; kt < K; kt += BK) {
        __syncthreads();
        #pragma unroll
        for (int q = 0; q < 2; q++) {
            int ch = q * 256 + tid;
            int r = ch >> 2, kk = (ch & 3) << 3;
            size_t ga = (size_t)(rA0 + r) * K + kt + kk;
            size_t gb = (size_t)(cB0 + r) * K + kt + kk;
            char* la0 = (char*)&As[0][0][0] + (q * 256 + wave * 64) * 16;
            char* lb0 = (char*)&Bs[0][0][0] + (q * 256 + wave * 64) * 16;
            gl_lds16(&Ah[ga], la0);
            gl_lds16(&Bh[gb], lb0);
            if constexpr (SPLIT) {
                char* la1 = (char*)&As[1][0][0] + (q * 256 + wave * 64) * 16;
                char* lb1 = (char*)&Bs[1][0][0] + (q * 256 + wave * 64) * 16;
                gl_lds16(&Al[ga], la1);
                gl_lds16(&Bl[gb], lb1);
            }
        }
        __syncthreads();

        bf16x8 afh[4], bfh[4], afl[4], bfl[4];
        #pragma unroll
        for (int m = 0; m < 4; m++) afh[m] = *(const bf16x8*)&As[0][wr * 64 + m * 16 + fr][fg * 8];
        #pragma unroll
        for (int n = 0; n < 4; n++) bfh[n] = *(const bf16x8*)&Bs[0][wc * 64 + n * 16 + fr][fg * 8];
        if constexpr (SPLIT) {
            #pragma unroll
            for (int m = 0; m < 4; m++) afl[m] = *(const bf16x8*)&As[1][wr * 64 + m * 16 + fr][fg * 8];
            #pragma unroll
            for (int n = 0; n < 4; n++) bfl[n] = *(const bf16x8*)&Bs[1][wc * 64 + n * 16 + fr][fg * 8];
        }
        #pragma unroll
        for (int m = 0; m < 4; m++)
            #pragma unroll
            for (int n = 0; n < 4; n++) {
                acc[m][n] = MFMA_BF16(afh[m], bfh[n], acc[m][n]);
                if constexpr (SPLIT) {
                    acc[m][n] = MFMA_BF16(afl[m], bfh[n], acc[m][n]);
                    acc[m][n] = MFMA_BF16(afh[m], bfl[n], acc[m][n]);
                }
            }
    }

    #pragma unroll
    for (int m = 0; m < 4; m++) {
        #pragma unroll
        for (int n = 0; n < 4; n++) {
            #pragma unroll
            for (int j = 0; j < 4; j++) {
                int row = rA0 + wr * 64 + m * 16 + fg * 4 + j;
                int col = cB0 + wc * 64 + n * 16 + fr;
                float v = acc[m][n][j];
                if constexpr (EPI == 1) {
                    v += bias[col];
                    v = fmaxf(v, 0.f);
                    Cb[(size_t)row * N + col] = f2bf(v);
                } else {  // EPI == 3: col = t*512 + h*64 + k (t:0=Q,1=K); row = b*2048+tt
                    int t = col >> 9, h = (col >> 6) & 7, k = col & 63;
                    int b = row >> 11, tt = row & 2047;
                    size_t di = ((size_t)((b << 3) + h) * 2048 + tt) * 64 + k;
                    unsigned short hh = f2bf(v);
                    if (t == 0) { Qh[di] = hh; Ql[di] = f2bf(v - bf2f(hh)); }
                    else        { Kh[di] = hh; Kl[di] = f2bf(v - bf2f(hh)); }
                }
            }
        }
    }
}

// ---------------- GEMM 64x64 (4 waves, 32x32/wave) for skinny shapes -------
// EPI: 0 = bf16 out, 2 = bias f32 out, 4 = Vt scatter
template<int EPI>
__global__ __launch_bounds__(256)
void gemm64(const unsigned short* __restrict__ A, const unsigned short* __restrict__ Bt,
            int M, int N, int K, const float* __restrict__ bias,
            unsigned short* __restrict__ Cb, float* __restrict__ Cf,
            unsigned short* __restrict__ Vo)
{
    constexpr int BK = 32;
    __shared__ __align__(16) unsigned short As[64][BK];
    __shared__ __align__(16) unsigned short Bs[64][BK];

    const int tid = threadIdx.x, lane = tid & 63, wave = tid >> 6;
    const int wr = wave >> 1, wc = wave & 1;
    const int rA0 = blockIdx.y * 64, cB0 = blockIdx.x * 64;
    const int fr = lane & 15, fg = lane >> 4;

    f32x4 acc[2][2];
    #pragma unroll
    for (int m = 0; m < 2; m++)
        #pragma unroll
        for (int n = 0; n < 2; n++)
            acc[m][n] = f32x4{0.f, 0.f, 0.f, 0.f};

    const int r = tid >> 2, kk = (tid & 3) << 3;
    for (int kt = 0; kt < K; kt += BK) {
        __syncthreads();
        gl_lds16(&A [(size_t)(rA0 + r) * K + kt + kk], (char*)&As[0][0] + wave * 1024);
        gl_lds16(&Bt[(size_t)(cB0 + r) * K + kt + kk], (char*)&Bs[0][0] + wave * 1024);
        __syncthreads();

        bf16x8 af[2], bf[2];
        #pragma unroll
        for (int m = 0; m < 2; m++) af[m] = *(const bf16x8*)&As[wr * 32 + m * 16 + fr][fg * 8];
        #pragma unroll
        for (int n = 0; n < 2; n++) bf[n] = *(const bf16x8*)&Bs[wc * 32 + n * 16 + fr][fg * 8];
        #pragma unroll
        for (int m = 0; m < 2; m++)
            #pragma unroll
            for (int n = 0; n < 2; n++)
                acc[m][n] = MFMA_BF16(af[m], bf[n], acc[m][n]);
    }

    #pragma unroll
    for (int m = 0; m < 2; m++) {
        #pragma unroll
        for (int n = 0; n < 2; n++) {
            #pragma unroll
            for (int j = 0; j < 4; j++) {
                int row = rA0 + wr * 32 + m * 16 + fg * 4 + j;
                int col = cB0 + wc * 32 + n * 16 + fr;
                float v = acc[m][n][j];
                if constexpr (EPI == 2) v += bias[col];
                if constexpr (EPI == 0) {
                    Cb[(size_t)row * N + col] = f2bf(v);
                } else if constexpr (EPI == 2) {
                    Cf[(size_t)row * N + col] = v;
                } else {  // EPI==4: row = h*64+k, col = b*2048+t -> Vt[((b*8+h)*64+k)*2048+t]
                    int h = row >> 6, k = row & 63;
                    int b = col >> 11, tt = col & 2047;
                    Vo[(((size_t)(b * 8 + h) * 64 + k) << 11) + tt] = f2bf(v);
                }
            }
        }
    }
}

// ---------------- flash attention (split-precision QK^T, pre-transposed V) --
// 8 waves x 16 q-rows = 128 q-rows per block sharing one K/V staging.
// grid.x = B*H*(T/128) = 512; 64 keys per iteration.
__global__ __launch_bounds__(512)
void attn_kernel(const unsigned short* __restrict__ Qh, const unsigned short* __restrict__ Ql,
                 const unsigned short* __restrict__ Kh, const unsigned short* __restrict__ Kl,
                 const unsigned short* __restrict__ Vt, unsigned short* __restrict__ Ob)
{
    constexpr int T = 2048;
    __shared__ __align__(16) unsigned short Ksh[64][72];     // K hi rows (s-major), padded
    __shared__ __align__(16) unsigned short Ksl[64][72];     // K lo rows
    __shared__ __align__(16) unsigned short Vts[64 * 64];    // [v][s], XOR-swizzled 16B slots
    __shared__ __align__(16) unsigned short Plds[8][16][72]; // per-wave P, [q][s]

    const int tid = threadIdx.x, lane = tid & 63, wave = tid >> 6;
    const int bh = blockIdx.x >> 4;
    const int q0 = (blockIdx.x & 15) * 128;
    const size_t base = (size_t)bh * T * 64;
    const int fr = lane & 15, fg = lane >> 4;

    const size_t qoff = base + (size_t)(q0 + wave * 16 + fr) * 64;
    bf16x8 aq0h = *(const bf16x8*)&Qh[qoff + fg * 8];
    bf16x8 aq1h = *(const bf16x8*)&Qh[qoff + 32 + fg * 8];
    bf16x8 aq0l = *(const bf16x8*)&Ql[qoff + fg * 8];
    bf16x8 aq1l = *(const bf16x8*)&Ql[qoff + 32 + fg * 8];

    f32x4 o[4];
    #pragma unroll
    for (int n = 0; n < 4; n++) o[n] = f32x4{0.f, 0.f, 0.f, 0.f};
    float mrun[4] = {-1e30f, -1e30f, -1e30f, -1e30f};
    float lrun[4] = {0.f, 0.f, 0.f, 0.f};

    const int srow = tid >> 3, c8 = (tid & 7) << 3;   // 512 threads: rows 0..63, slots 0..7
    char* vbase = (char*)Vts;

    for (int s0 = 0; s0 < T; s0 += 64) {
        __syncthreads();
        {
            size_t g = base + (size_t)(s0 + srow) * 64 + c8;
            *(uint4*)&Ksh[srow][c8] = *(const uint4*)&Kh[g];
            *(uint4*)&Ksl[srow][c8] = *(const uint4*)&Kl[g];
            // V^T tile: rows = v, cols = s; global Vt[(bh*64+v)*2048 + s0 + c8]
            uint4 vv = *(const uint4*)&Vt[((size_t)(bh * 64 + srow) << 11) + s0 + c8];
            int byteoff = srow * 128 + ((c8 * 2) ^ ((srow & 7) << 4));
            *(uint4*)(vbase + byteoff) = vv;
        }
        __syncthreads();

        // scores: S = Q (16x64) . K^T (64x64), split hi/lo -> four 16x16 fragments
        f32x4 sc[4];
        #pragma unroll
        for (int c = 0; c < 4; c++) {
            bf16x8 b0h = *(const bf16x8*)&Ksh[c * 16 + fr][fg * 8];
            bf16x8 b1h = *(const bf16x8*)&Ksh[c * 16 + fr][32 + fg * 8];
            bf16x8 b0l = *(const bf16x8*)&Ksl[c * 16 + fr][fg * 8];
            bf16x8 b1l = *(const bf16x8*)&Ksl[c * 16 + fr][32 + fg * 8];
            f32x4 z = f32x4{0.f, 0.f, 0.f, 0.f};
            z = MFMA_BF16(aq0h, b0h, z);
            z = MFMA_BF16(aq0l, b0h, z);
            z = MFMA_BF16(aq0h, b0l, z);
            z = MFMA_BF16(aq1h, b1h, z);
            z = MFMA_BF16(aq1l, b1h, z);
            z = MFMA_BF16(aq1h, b1l, z);
            sc[c] = z * 0.125f;   // 1/sqrt(64)
        }

        // online softmax (rows live across the 16-lane group; 4 rows/lane)
        float alpha[4];
        #pragma unroll
        for (int r2 = 0; r2 < 4; r2++) {
            float v = fmaxf(fmaxf(sc[0][r2], sc[1][r2]), fmaxf(sc[2][r2], sc[3][r2]));
            v = fmaxf(v, __shfl_xor(v, 1)); v = fmaxf(v, __shfl_xor(v, 2));
            v = fmaxf(v, __shfl_xor(v, 4)); v = fmaxf(v, __shfl_xor(v, 8));
            float mn = fmaxf(mrun[r2], v);
            alpha[r2] = __expf(mrun[r2] - mn);
            mrun[r2] = mn;
        }
        float rs[4] = {0.f, 0.f, 0.f, 0.f};
        #pragma unroll
        for (int c = 0; c < 4; c++)
            #pragma unroll
            for (int r2 = 0; r2 < 4; r2++) {
                float p = __expf(sc[c][r2] - mrun[r2]);
                sc[c][r2] = p;
                rs[r2] += p;
            }
        #pragma unroll
        for (int r2 = 0; r2 < 4; r2++) {
            float t = rs[r2];
            t += __shfl_xor(t, 1); t += __shfl_xor(t, 2);
            t += __shfl_xor(t, 4); t += __shfl_xor(t, 8);
            lrun[r2] = lrun[r2] * alpha[r2] + t;
            #pragma unroll
            for (int n = 0; n < 4; n++) o[n][r2] *= alpha[r2];
        }

        // P (D-layout) -> LDS -> A-layout for PV
        #pragma unroll
        for (int c = 0; c < 4; c++)
            #pragma unroll
            for (int r2 = 0; r2 < 4; r2++)
                Plds[wave][fg * 4 + r2][c * 16 + fr] = f2bf(sc[c][r2]);
        __syncthreads();

        bf16x8 pa0 = *(const bf16x8*)&Plds[wave][fr][fg * 8];
        bf16x8 pa1 = *(const bf16x8*)&Plds[wave][fr][32 + fg * 8];
        #pragma unroll
        for (int n = 0; n < 4; n++) {
            int row = n * 16 + fr;
            bf16x8 bv0 = *(const bf16x8*)(vbase + row * 128 + ((fg * 16)      ^ ((row & 7) << 4)));
            bf16x8 bv1 = *(const bf16x8*)(vbase + row * 128 + ((64 + fg * 16) ^ ((row & 7) << 4)));
            o[n] = MFMA_BF16(pa0, bv0, o[n]);
            o[n] = MFMA_BF16(pa1, bv1, o[n]);
        }
    }

    #pragma unroll
    for (int r2 = 0; r2 < 4; r2++) {
        float inv = 1.0f / lrun[r2];
        #pragma unroll
        for (int n = 0; n < 4; n++) o[n][r2] *= inv;
    }
    #pragma unroll
    for (int n = 0; n < 4; n++)
        #pragma unroll
        for (int r2 = 0; r2 < 4; r2++)
            Ob[base + (size_t)(q0 + wave * 16 + fg * 4 + r2) * 64 + n * 16 + fr] = f2bf(o[n][r2]);
}

// ---------------- launch ----------------
extern "C" void kernel_launch(void* const* d_in, const int* in_sizes, int n_in,
                              void* d_out, int out_size, void* d_ws, size_t ws_size,
                              hipStream_t stream)
{
    const float* x  = (const float*)d_in[0];
    const float* Wq = (const float*)d_in[1];
    const float* Wk = (const float*)d_in[2];
    const float* Wv = (const float*)d_in[3];
    const float* Wo = (const float*)d_in[4];
    const float* W1 = (const float*)d_in[5];
    const float* b1 = (const float*)d_in[6];
    const float* W2 = (const float*)d_in[7];
    const float* b2 = (const float*)d_in[8];
    float* out = (float*)d_out;

    char* ws = (char*)d_ws;
    size_t off = 0;
    auto alloc = [&](size_t bytes) -> void* {
        void* p = ws + off; off += (bytes + 255) & ~(size_t)255; return p;
    };
    unsigned short* wqkTh = (unsigned short*)alloc(1024ull * 512 * 2);
    unsigned short* wqkTl = (unsigned short*)alloc(1024ull * 512 * 2);
    unsigned short* wvT   = (unsigned short*)alloc(512ull * 512 * 2);
    unsigned short* woT   = (unsigned short*)alloc(512ull * 512 * 2);
    unsigned short* w1T   = (unsigned short*)alloc(2048ull * 512 * 2);
    unsigned short* w2T   = (unsigned short*)alloc(512ull * 2048 * 2);
    unsigned short* Qhb   = (unsigned short*)alloc(8192ull * 512 * 2);
    unsigned short* Qlb   = (unsigned short*)alloc(8192ull * 512 * 2);
    unsigned short* Khb   = (unsigned short*)alloc(8192ull * 512 * 2);
    unsigned short* Klb   = (unsigned short*)alloc(8192ull * 512 * 2);
    unsigned short* Vtb   = (unsigned short*)alloc(8192ull * 512 * 2);
    unsigned short* xh    = (unsigned short*)alloc(8192ull * 512 * 2);
    unsigned short* xl    = (unsigned short*)alloc(8192ull * 512 * 2);
    // aliases (lifetimes do not overlap):
    unsigned short* attb = xh;   // attn out, after QK/Vt GEMMs consumed xh/xl
    unsigned short* outb = xl;   // Wo out
    unsigned short* hb   = Qhb;  // FF1 out (32MB across Qh..Kl), after attention

    k_cvt_split<<<8192 * 512 / 4 / 256, 256, 0, stream>>>(
        (const float4*)x, (ushort4*)xh, (ushort4*)xl, 8192 * 512 / 4);
    k_transT<<<dim3(2, 16, 8), 256, 0, stream>>>(Wq, 512 * 64, wqkTh, wqkTl, 512, 64, 0);
    k_transT<<<dim3(2, 16, 8), 256, 0, stream>>>(Wk, 512 * 64, wqkTh, wqkTl, 512, 64, 512 * 512);
    k_transT<<<dim3(2, 16, 8), 256, 0, stream>>>(Wv, 512 * 64, wvT, nullptr, 512, 64, 0);
    k_transT<<<dim3(16, 16, 1), 256, 0, stream>>>(Wo, 0, woT, nullptr, 512, 512, 0);
    k_transT<<<dim3(64, 16, 1), 256, 0, stream>>>(W1, 0, w1T, nullptr, 512, 2048, 0);
    k_transT<<<dim3(16, 64, 1), 256, 0, stream>>>(W2, 0, w2T, nullptr, 2048, 512, 0);

    // QK projection (split precision): (8192x512) @ (512x1024) -> Q/K hi+lo
    gemm_bt<3, true><<<dim3(1024 / 128, 8192 / 128), 256, 0, stream>>>(
        xh, xl, wqkTh, wqkTl, 8192, 1024, 512, nullptr,
        nullptr, nullptr, Qhb, Qlb, Khb, Klb, nullptr);

    // V^T projection (64x64 tiles): rows = (h,k) 512, cols = (b,t) 8192 -> Vt
    gemm64<4><<<dim3(8192 / 64, 512 / 64), 256, 0, stream>>>(
        wvT, xh, 512, 8192, 512, nullptr, nullptr, nullptr, Vtb);

    // attention (8-wave) -> attb (B,H,T,64) flat == (B,T',512)
    attn_kernel<<<4 * 8 * (2048 / 128), 512, 0, stream>>>(Qhb, Qlb, Khb, Klb, Vtb, attb);

    // out = att' @ Wo   (64x64 tiles)
    gemm64<0><<<dim3(512 / 64, 8192 / 64), 256, 0, stream>>>(
        attb, woT, 8192, 512, 512, nullptr, outb, nullptr, nullptr);

    // h = relu(out @ W1 + b1)   (128x128 tiles)
    gemm_bt<1, false><<<dim3(2048 / 128, 8192 / 128), 256, 0, stream>>>(
        outb, nullptr, w1T, nullptr, 8192, 2048, 512, b1,
        hb, nullptr, nullptr, nullptr, nullptr, nullptr, nullptr);

    // y = h @ W2 + b2  (f32 output; 64x64 tiles)
    gemm64<2><<<dim3(512 / 64, 8192 / 64), 256, 0, stream>>>(
        hb, w2T, 8192, 512, 2048, b2, nullptr, out, nullptr);
}

// Round 11
// 343.159 us; speedup vs baseline: 1.4415x; 1.0569x over previous
//
#include <hip/hip_runtime.h>
#include <hip/hip_bf16.h>

typedef short bf16x8 __attribute__((ext_vector_type(8)));
typedef float f32x4 __attribute__((ext_vector_type(4)));

#define MFMA_BF16(A,B,C) __builtin_amdgcn_mfma_f32_16x16x32_bf16((A),(B),(C),0,0,0)

__device__ __forceinline__ unsigned short f2bf(float f){
    union { float f; unsigned u; } v; v.f = f;
    unsigned r = v.u + 0x7fffu + ((v.u >> 16) & 1u);
    return (unsigned short)(r >> 16);
}
__device__ __forceinline__ float bf2f(unsigned short h){
    union { unsigned u; float f; } v; v.u = ((unsigned)h) << 16; return v.f;
}

// async global->LDS, 16B per lane; lds dest = wave-uniform base (+lane*16 implicit)
__device__ __forceinline__ void gl_lds16(const unsigned short* g, void* l){
    __builtin_amdgcn_global_load_lds(
        (const __attribute__((address_space(1))) unsigned int*)g,
        (__attribute__((address_space(3))) unsigned int*)l, 16, 0, 0);
}

// ---------------- prep kernels ----------------
__global__ __launch_bounds__(256) void k_cvt_split(const float4* __restrict__ in,
                                                   ushort4* __restrict__ hi,
                                                   ushort4* __restrict__ lo, int n4){
    int i = blockIdx.x * 256 + threadIdx.x;
    if (i < n4) {
        float4 v = in[i];
        ushort4 h, l;
        h.x = f2bf(v.x); l.x = f2bf(v.x - bf2f(h.x));
        h.y = f2bf(v.y); l.y = f2bf(v.y - bf2f(h.y));
        h.z = f2bf(v.z); l.z = f2bf(v.z - bf2f(h.z));
        h.w = f2bf(v.w); l.w = f2bf(v.w - bf2f(h.w));
        hi[i] = h; lo[i] = l;
    }
}

// tiled transpose+cast (+optional split): in f32 (R x C) per head -> out bf16 (C x R)
__global__ __launch_bounds__(256)
void k_transT(const float* __restrict__ in, long inHeadStride,
              unsigned short* __restrict__ hi, unsigned short* __restrict__ lo,
              int R, int C, long outBase){
    __shared__ float t[32][33];
    const float* src = in + (size_t)blockIdx.z * inHeadStride;
    int c0 = blockIdx.x * 32, r0 = blockIdx.y * 32;
    int tx = threadIdx.x & 31, ty = threadIdx.x >> 5;   // 32 x 8
    #pragma unroll
    for (int i = 0; i < 4; i++)
        t[ty + i * 8][tx] = src[(size_t)(r0 + ty + i * 8) * C + c0 + tx];
    __syncthreads();
    size_t ob = (size_t)outBase + (size_t)blockIdx.z * C * R;
    #pragma unroll
    for (int i = 0; i < 4; i++) {
        int c = c0 + ty + i * 8, r = r0 + tx;
        float v = t[tx][ty + i * 8];
        unsigned short hh = f2bf(v);
        hi[ob + (size_t)c * R + r] = hh;
        if (lo) lo[ob + (size_t)c * R + r] = f2bf(v - bf2f(hh));
    }
}

// ---------------- GEMM 128x128: C = A(MxK) * Bt(NxK)^T ----------------
// EPI: 1 = bias+relu bf16 out, 3 = QK split scatter
template<int EPI, bool SPLIT>
__global__ __launch_bounds__(256)
void gemm_bt(const unsigned short* __restrict__ Ah, const unsigned short* __restrict__ Al,
             const unsigned short* __restrict__ Bh, const unsigned short* __restrict__ Bl,
             int M, int N, int K, const float* __restrict__ bias,
             unsigned short* __restrict__ Cb, float* __restrict__ Cf,
             unsigned short* __restrict__ Qh, unsigned short* __restrict__ Ql,
             unsigned short* __restrict__ Kh, unsigned short* __restrict__ Kl,
             unsigned short* __restrict__ Vo)
{
    constexpr int BK = 32;
    constexpr int NS = SPLIT ? 2 : 1;
    __shared__ __align__(16) unsigned short As[NS][128][BK];
    __shared__ __align__(16) unsigned short Bs[NS][128][BK];

    const int tid = threadIdx.x, lane = tid & 63, wave = tid >> 6;
    const int wr = wave >> 1, wc = wave & 1;
    const int rA0 = blockIdx.y * 128, cB0 = blockIdx.x * 128;
    const int fr = lane & 15, fg = lane >> 4;

    f32x4 acc[4][4];
    #pragma unroll
    for (int m = 0; m < 4; m++)
        #pragma unroll
        for (int n = 0; n < 4; n++)
            acc[m][n] = f32x4{0.f, 0.f, 0.f, 0.f};

    for (int kt = 0; kt < K; kt += BK) {
        __syncthreads();
        #pragma unroll
        for (int q = 0; q < 2; q++) {
            int ch = q * 256 + tid;
            int r = ch >> 2, kk = (ch & 3) << 3;
            size_t ga = (size_t)(rA0 + r) * K + kt + kk;
            size_t gb = (size_t)(cB0 + r) * K + kt + kk;
            char* la0 = (char*)&As[0][0][0] + (q * 256 + wave * 64) * 16;
            char* lb0 = (char*)&Bs[0][0][0] + (q * 256 + wave * 64) * 16;
            gl_lds16(&Ah[ga], la0);
            gl_lds16(&Bh[gb], lb0);
            if constexpr (SPLIT) {
                char* la1 = (char*)&As[1][0][0] + (q * 256 + wave * 64) * 16;
                char* lb1 = (char*)&Bs[1][0][0] + (q * 256 + wave * 64) * 16;
                gl_lds16(&Al[ga], la1);
                gl_lds16(&Bl[gb], lb1);
            }
        }
        __syncthreads();

        bf16x8 afh[4], bfh[4], afl[4], bfl[4];
        #pragma unroll
        for (int m = 0; m < 4; m++) afh[m] = *(const bf16x8*)&As[0][wr * 64 + m * 16 + fr][fg * 8];
        #pragma unroll
        for (int n = 0; n < 4; n++) bfh[n] = *(const bf16x8*)&Bs[0][wc * 64 + n * 16 + fr][fg * 8];
        if constexpr (SPLIT) {
            #pragma unroll
            for (int m = 0; m < 4; m++) afl[m] = *(const bf16x8*)&As[1][wr * 64 + m * 16 + fr][fg * 8];
            #pragma unroll
            for (int n = 0; n < 4; n++) bfl[n] = *(const bf16x8*)&Bs[1][wc * 64 + n * 16 + fr][fg * 8];
        }
        #pragma unroll
        for (int m = 0; m < 4; m++)
            #pragma unroll
            for (int n = 0; n < 4; n++) {
                acc[m][n] = MFMA_BF16(afh[m], bfh[n], acc[m][n]);
                if constexpr (SPLIT) {
                    acc[m][n] = MFMA_BF16(afl[m], bfh[n], acc[m][n]);
                    acc[m][n] = MFMA_BF16(afh[m], bfl[n], acc[m][n]);
                }
            }
    }

    #pragma unroll
    for (int m = 0; m < 4; m++) {
        #pragma unroll
        for (int n = 0; n < 4; n++) {
            #pragma unroll
            for (int j = 0; j < 4; j++) {
                int row = rA0 + wr * 64 + m * 16 + fg * 4 + j;
                int col = cB0 + wc * 64 + n * 16 + fr;
                float v = acc[m][n][j];
                if constexpr (EPI == 1) {
                    v += bias[col];
                    v = fmaxf(v, 0.f);
                    Cb[(size_t)row * N + col] = f2bf(v);
                } else {  // EPI == 3: col = t*512 + h*64 + k (t:0=Q,1=K); row = b*2048+tt
                    int t = col >> 9, h = (col >> 6) & 7, k = col & 63;
                    int b = row >> 11, tt = row & 2047;
                    size_t di = ((size_t)((b << 3) + h) * 2048 + tt) * 64 + k;
                    unsigned short hh = f2bf(v);
                    if (t == 0) { Qh[di] = hh; Ql[di] = f2bf(v - bf2f(hh)); }
                    else        { Kh[di] = hh; Kl[di] = f2bf(v - bf2f(hh)); }
                }
            }
        }
    }
}

// ---------------- GEMM 64x64 (4 waves, 32x32/wave) for skinny shapes -------
// EPI: 0 = bf16 out, 2 = bias f32 out, 4 = Vt scatter
template<int EPI>
__global__ __launch_bounds__(256)
void gemm64(const unsigned short* __restrict__ A, const unsigned short* __restrict__ Bt,
            int M, int N, int K, const float* __restrict__ bias,
            unsigned short* __restrict__ Cb, float* __restrict__ Cf,
            unsigned short* __restrict__ Vo)
{
    constexpr int BK = 32;
    __shared__ __align__(16) unsigned short As[64][BK];
    __shared__ __align__(16) unsigned short Bs[64][BK];

    const int tid = threadIdx.x, lane = tid & 63, wave = tid >> 6;
    const int wr = wave >> 1, wc = wave & 1;
    const int rA0 = blockIdx.y * 64, cB0 = blockIdx.x * 64;
    const int fr = lane & 15, fg = lane >> 4;

    f32x4 acc[2][2];
    #pragma unroll
    for (int m = 0; m < 2; m++)
        #pragma unroll
        for (int n = 0; n < 2; n++)
            acc[m][n] = f32x4{0.f, 0.f, 0.f, 0.f};

    const int r = tid >> 2, kk = (tid & 3) << 3;
    for (int kt = 0; kt < K; kt += BK) {
        __syncthreads();
        gl_lds16(&A [(size_t)(rA0 + r) * K + kt + kk], (char*)&As[0][0] + wave * 1024);
        gl_lds16(&Bt[(size_t)(cB0 + r) * K + kt + kk], (char*)&Bs[0][0] + wave * 1024);
        __syncthreads();

        bf16x8 af[2], bf[2];
        #pragma unroll
        for (int m = 0; m < 2; m++) af[m] = *(const bf16x8*)&As[wr * 32 + m * 16 + fr][fg * 8];
        #pragma unroll
        for (int n = 0; n < 2; n++) bf[n] = *(const bf16x8*)&Bs[wc * 32 + n * 16 + fr][fg * 8];
        #pragma unroll
        for (int m = 0; m < 2; m++)
            #pragma unroll
            for (int n = 0; n < 2; n++)
                acc[m][n] = MFMA_BF16(af[m], bf[n], acc[m][n]);
    }

    #pragma unroll
    for (int m = 0; m < 2; m++) {
        #pragma unroll
        for (int n = 0; n < 2; n++) {
            #pragma unroll
            for (int j = 0; j < 4; j++) {
                int row = rA0 + wr * 32 + m * 16 + fg * 4 + j;
                int col = cB0 + wc * 32 + n * 16 + fr;
                float v = acc[m][n][j];
                if constexpr (EPI == 2) v += bias[col];
                if constexpr (EPI == 0) {
                    Cb[(size_t)row * N + col] = f2bf(v);
                } else if constexpr (EPI == 2) {
                    Cf[(size_t)row * N + col] = v;
                } else {  // EPI==4: row = h*64+k, col = b*2048+t -> Vt[((b*8+h)*64+k)*2048+t]
                    int h = row >> 6, k = row & 63;
                    int b = col >> 11, tt = col & 2047;
                    Vo[(((size_t)(b * 8 + h) * 64 + k) << 11) + tt] = f2bf(v);
                }
            }
        }
    }
}

// ---------------- flash attention (split-precision QK^T, pre-transposed V) --
// 8 waves x 16 q-rows = 128 q-rows per block; 64 keys/iter.
// T14 async-STAGE: next tile's global loads issued right after staging barrier,
// ds_write deferred to next iteration top. Post-P barrier removed (Plds per-wave).
__global__ __launch_bounds__(512)
void attn_kernel(const unsigned short* __restrict__ Qh, const unsigned short* __restrict__ Ql,
                 const unsigned short* __restrict__ Kh, const unsigned short* __restrict__ Kl,
                 const unsigned short* __restrict__ Vt, unsigned short* __restrict__ Ob)
{
    constexpr int T = 2048;
    __shared__ __align__(16) unsigned short Ksh[64][72];     // K hi rows (s-major), padded
    __shared__ __align__(16) unsigned short Ksl[64][72];     // K lo rows
    __shared__ __align__(16) unsigned short Vts[64 * 64];    // [v][s], XOR-swizzled 16B slots
    __shared__ __align__(16) unsigned short Plds[8][16][72]; // per-wave P, [q][s]

    const int tid = threadIdx.x, lane = tid & 63, wave = tid >> 6;
    const int bh = blockIdx.x >> 4;
    const int q0 = (blockIdx.x & 15) * 128;
    const size_t base = (size_t)bh * T * 64;
    const int fr = lane & 15, fg = lane >> 4;

    const size_t qoff = base + (size_t)(q0 + wave * 16 + fr) * 64;
    bf16x8 aq0h = *(const bf16x8*)&Qh[qoff + fg * 8];
    bf16x8 aq1h = *(const bf16x8*)&Qh[qoff + 32 + fg * 8];
    bf16x8 aq0l = *(const bf16x8*)&Ql[qoff + fg * 8];
    bf16x8 aq1l = *(const bf16x8*)&Ql[qoff + 32 + fg * 8];

    f32x4 o[4];
    #pragma unroll
    for (int n = 0; n < 4; n++) o[n] = f32x4{0.f, 0.f, 0.f, 0.f};
    float mrun[4] = {-1e30f, -1e30f, -1e30f, -1e30f};
    float lrun[4] = {0.f, 0.f, 0.f, 0.f};

    const int srow = tid >> 3, c8 = (tid & 7) << 3;   // 512 threads: rows 0..63, slots 0..7
    char* vbase = (char*)Vts;
    const int vbyteoff = srow * 128 + ((c8 * 2) ^ ((srow & 7) << 4));

    // register-staged tile (T14)
    uint4 rkh, rkl, rvv;
    {
        size_t g = base + (size_t)srow * 64 + c8;
        rkh = *(const uint4*)&Kh[g];
        rkl = *(const uint4*)&Kl[g];
        rvv = *(const uint4*)&Vt[((size_t)(bh * 64 + srow) << 11) + c8];
    }

    for (int s0 = 0; s0 < T; s0 += 64) {
        __syncthreads();                 // all waves done reading previous tile's LDS
        *(uint4*)&Ksh[srow][c8] = rkh;
        *(uint4*)&Ksl[srow][c8] = rkl;
        *(uint4*)(vbase + vbyteoff) = rvv;
        __syncthreads();

        if (s0 + 64 < T) {               // issue next tile's loads; hide under compute
            size_t g = base + (size_t)(s0 + 64 + srow) * 64 + c8;
            rkh = *(const uint4*)&Kh[g];
            rkl = *(const uint4*)&Kl[g];
            rvv = *(const uint4*)&Vt[((size_t)(bh * 64 + srow) << 11) + s0 + 64 + c8];
        }

        // scores: S = Q (16x64) . K^T (64x64), split hi/lo -> four 16x16 fragments
        f32x4 sc[4];
        #pragma unroll
        for (int c = 0; c < 4; c++) {
            bf16x8 b0h = *(const bf16x8*)&Ksh[c * 16 + fr][fg * 8];
            bf16x8 b1h = *(const bf16x8*)&Ksh[c * 16 + fr][32 + fg * 8];
            bf16x8 b0l = *(const bf16x8*)&Ksl[c * 16 + fr][fg * 8];
            bf16x8 b1l = *(const bf16x8*)&Ksl[c * 16 + fr][32 + fg * 8];
            f32x4 z = f32x4{0.f, 0.f, 0.f, 0.f};
            z = MFMA_BF16(aq0h, b0h, z);
            z = MFMA_BF16(aq0l, b0h, z);
            z = MFMA_BF16(aq0h, b0l, z);
            z = MFMA_BF16(aq1h, b1h, z);
            z = MFMA_BF16(aq1l, b1h, z);
            z = MFMA_BF16(aq1h, b1l, z);
            sc[c] = z * 0.125f;   // 1/sqrt(64)
        }

        // online softmax (rows live across the 16-lane group; 4 rows/lane)
        float alpha[4];
        #pragma unroll
        for (int r2 = 0; r2 < 4; r2++) {
            float v = fmaxf(fmaxf(sc[0][r2], sc[1][r2]), fmaxf(sc[2][r2], sc[3][r2]));
            v = fmaxf(v, __shfl_xor(v, 1)); v = fmaxf(v, __shfl_xor(v, 2));
            v = fmaxf(v, __shfl_xor(v, 4)); v = fmaxf(v, __shfl_xor(v, 8));
            float mn = fmaxf(mrun[r2], v);
            alpha[r2] = __expf(mrun[r2] - mn);
            mrun[r2] = mn;
        }
        float rs[4] = {0.f, 0.f, 0.f, 0.f};
        #pragma unroll
        for (int c = 0; c < 4; c++)
            #pragma unroll
            for (int r2 = 0; r2 < 4; r2++) {
                float p = __expf(sc[c][r2] - mrun[r2]);
                sc[c][r2] = p;
                rs[r2] += p;
            }
        #pragma unroll
        for (int r2 = 0; r2 < 4; r2++) {
            float t = rs[r2];
            t += __shfl_xor(t, 1); t += __shfl_xor(t, 2);
            t += __shfl_xor(t, 4); t += __shfl_xor(t, 8);
            lrun[r2] = lrun[r2] * alpha[r2] + t;
            #pragma unroll
            for (int n = 0; n < 4; n++) o[n][r2] *= alpha[r2];
        }

        // P (D-layout) -> per-wave LDS -> A-layout (intra-wave: no block barrier needed)
        #pragma unroll
        for (int c = 0; c < 4; c++)
            #pragma unroll
            for (int r2 = 0; r2 < 4; r2++)
                Plds[wave][fg * 4 + r2][c * 16 + fr] = f2bf(sc[c][r2]);

        bf16x8 pa0 = *(const bf16x8*)&Plds[wave][fr][fg * 8];
        bf16x8 pa1 = *(const bf16x8*)&Plds[wave][fr][32 + fg * 8];
        #pragma unroll
        for (int n = 0; n < 4; n++) {
            int row = n * 16 + fr;
            bf16x8 bv0 = *(const bf16x8*)(vbase + row * 128 + ((fg * 16)      ^ ((row & 7) << 4)));
            bf16x8 bv1 = *(const bf16x8*)(vbase + row * 128 + ((64 + fg * 16) ^ ((row & 7) << 4)));
            o[n] = MFMA_BF16(pa0, bv0, o[n]);
            o[n] = MFMA_BF16(pa1, bv1, o[n]);
        }
    }

    #pragma unroll
    for (int r2 = 0; r2 < 4; r2++) {
        float inv = 1.0f / lrun[r2];
        #pragma unroll
        for (int n = 0; n < 4; n++) o[n][r2] *= inv;
    }
    #pragma unroll
    for (int n = 0; n < 4; n++)
        #pragma unroll
        for (int r2 = 0; r2 < 4; r2++)
            Ob[base + (size_t)(q0 + wave * 16 + fg * 4 + r2) * 64 + n * 16 + fr] = f2bf(o[n][r2]);
}

// ---------------- launch ----------------
extern "C" void kernel_launch(void* const* d_in, const int* in_sizes, int n_in,
                              void* d_out, int out_size, void* d_ws, size_t ws_size,
                              hipStream_t stream)
{
    const float* x  = (const float*)d_in[0];
    const float* Wq = (const float*)d_in[1];
    const float* Wk = (const float*)d_in[2];
    const float* Wv = (const float*)d_in[3];
    const float* Wo = (const float*)d_in[4];
    const float* W1 = (const float*)d_in[5];
    const float* b1 = (const float*)d_in[6];
    const float* W2 = (const float*)d_in[7];
    const float* b2 = (const float*)d_in[8];
    float* out = (float*)d_out;

    char* ws = (char*)d_ws;
    size_t off = 0;
    auto alloc = [&](size_t bytes) -> void* {
        void* p = ws + off; off += (bytes + 255) & ~(size_t)255; return p;
    };
    unsigned short* wqkTh = (unsigned short*)alloc(1024ull * 512 * 2);
    unsigned short* wqkTl = (unsigned short*)alloc(1024ull * 512 * 2);
    unsigned short* wvT   = (unsigned short*)alloc(512ull * 512 * 2);
    unsigned short* woT   = (unsigned short*)alloc(512ull * 512 * 2);
    unsigned short* w1T   = (unsigned short*)alloc(2048ull * 512 * 2);
    unsigned short* w2T   = (unsigned short*)alloc(512ull * 2048 * 2);
    unsigned short* Qhb   = (unsigned short*)alloc(8192ull * 512 * 2);
    unsigned short* Qlb   = (unsigned short*)alloc(8192ull * 512 * 2);
    unsigned short* Khb   = (unsigned short*)alloc(8192ull * 512 * 2);
    unsigned short* Klb   = (unsigned short*)alloc(8192ull * 512 * 2);
    unsigned short* Vtb   = (unsigned short*)alloc(8192ull * 512 * 2);
    unsigned short* xh    = (unsigned short*)alloc(8192ull * 512 * 2);
    unsigned short* xl    = (unsigned short*)alloc(8192ull * 512 * 2);
    // aliases (lifetimes do not overlap):
    unsigned short* attb = xh;   // attn out, after QK/Vt GEMMs consumed xh/xl
    unsigned short* outb = xl;   // Wo out
    unsigned short* hb   = Qhb;  // FF1 out (32MB across Qh..Kl), after attention

    k_cvt_split<<<8192 * 512 / 4 / 256, 256, 0, stream>>>(
        (const float4*)x, (ushort4*)xh, (ushort4*)xl, 8192 * 512 / 4);
    k_transT<<<dim3(2, 16, 8), 256, 0, stream>>>(Wq, 512 * 64, wqkTh, wqkTl, 512, 64, 0);
    k_transT<<<dim3(2, 16, 8), 256, 0, stream>>>(Wk, 512 * 64, wqkTh, wqkTl, 512, 64, 512 * 512);
    k_transT<<<dim3(2, 16, 8), 256, 0, stream>>>(Wv, 512 * 64, wvT, nullptr, 512, 64, 0);
    k_transT<<<dim3(16, 16, 1), 256, 0, stream>>>(Wo, 0, woT, nullptr, 512, 512, 0);
    k_transT<<<dim3(64, 16, 1), 256, 0, stream>>>(W1, 0, w1T, nullptr, 512, 2048, 0);
    k_transT<<<dim3(16, 64, 1), 256, 0, stream>>>(W2, 0, w2T, nullptr, 2048, 512, 0);

    // QK projection (split precision): (8192x512) @ (512x1024) -> Q/K hi+lo
    gemm_bt<3, true><<<dim3(1024 / 128, 8192 / 128), 256, 0, stream>>>(
        xh, xl, wqkTh, wqkTl, 8192, 1024, 512, nullptr,
        nullptr, nullptr, Qhb, Qlb, Khb, Klb, nullptr);

    // V^T projection (64x64 tiles): rows = (h,k) 512, cols = (b,t) 8192 -> Vt
    gemm64<4><<<dim3(8192 / 64, 512 / 64), 256, 0, stream>>>(
        wvT, xh, 512, 8192, 512, nullptr, nullptr, nullptr, Vtb);

    // attention (8-wave, T14) -> attb (B,H,T,64) flat == (B,T',512)
    attn_kernel<<<4 * 8 * (2048 / 128), 512, 0, stream>>>(Qhb, Qlb, Khb, Klb, Vtb, attb);

    // out = att' @ Wo   (64x64 tiles)
    gemm64<0><<<dim3(512 / 64, 8192 / 64), 256, 0, stream>>>(
        attb, woT, 8192, 512, 512, nullptr, outb, nullptr, nullptr);

    // h = relu(out @ W1 + b1)   (128x128 tiles)
    gemm_bt<1, false><<<dim3(2048 / 128, 8192 / 128), 256, 0, stream>>>(
        outb, nullptr, w1T, nullptr, 8192, 2048, 512, b1,
        hb, nullptr, nullptr, nullptr, nullptr, nullptr, nullptr);

    // y = h @ W2 + b2  (f32 output; 64x64 tiles)
    gemm64<2><<<dim3(512 / 64, 8192 / 64), 256, 0, stream>>>(
        hb, w2T, 8192, 512, 2048, b2, nullptr, out, nullptr);
}